// Round 2
// baseline (425.165 us; speedup 1.0000x reference)
//
#include <hip/hip_runtime.h>
#include <math.h>

typedef unsigned short u16;
typedef __attribute__((ext_vector_type(8))) short short8;
typedef __attribute__((ext_vector_type(4))) float f32x4;

// Problem constants (B=8, N=2048, Nsrc=2048, C=512, H=W=64, sr_ratio=2 -> 32x32 grid)
#define BB     8
#define NN     2048
#define CC     512
#define HEADS  8
#define HD     64
#define GM     1024   // 32*32 spatial tokens per batch

// Workspace byte offsets (total ~82.6 MB)
#define B_FEATF   ((size_t)0)                    // feat fp32 16MB; later attn_bf (16MB)
#define B_XSF     ((size_t)16*1024*1024)         // xs fp32 16MB; later q_bf (16MB)
#define B_XBF     ((size_t)32*1024*1024)         // x bf16 16MB
#define B_KVBF    ((size_t)48*1024*1024)         // kv bf16 16MB
#define B_FEATBF  ((size_t)64*1024*1024)         // feat bf16 8MB
#define B_XSBF    ((size_t)72*1024*1024)         // xs bf16 8MB
#define B_CNT     ((size_t)80*1024*1024)         // 32KB
#define B_CONF    (B_CNT + (size_t)32*1024)      // 32KB
#define B_WQ      (B_CNT + (size_t)64*1024)      // 512KB
#define B_WKV     (B_WQ  + (size_t)512*1024)     // 1MB
#define B_WSR     (B_WKV + (size_t)1024*1024)    // 512KB
#define B_WPROJ   (B_WSR + (size_t)512*1024)     // 512KB

__device__ __forceinline__ u16 f2bf(float f) {
    unsigned u = __float_as_uint(f);
    unsigned r = (u + 0x7fffu + ((u >> 16) & 1u)) >> 16;   // RNE
    return (u16)r;
}

// ---------------------------------------------------------------------------
// fp32 -> bf16 cast (n4 float4-quads, grid*256 == n4)
// ---------------------------------------------------------------------------
__global__ __launch_bounds__(256) void cast_bf16_kernel(const float* __restrict__ in,
                                                        u16* __restrict__ out)
{
    const int i = blockIdx.x * 256 + threadIdx.x;
    const float4 v = ((const float4*)in)[i];
    ushort4 o;
    o.x = f2bf(v.x); o.y = f2bf(v.y); o.z = f2bf(v.z); o.w = f2bf(v.w);
    ((ushort4*)out)[i] = o;
}

// ---------------------------------------------------------------------------
// token2map scatter: one block per source token (fp32 atomics, exact)
// ---------------------------------------------------------------------------
__global__ __launch_bounds__(256) void scatter_kernel(const float* __restrict__ src_tok,
    const float* __restrict__ loc, const float* __restrict__ conf_src,
    float* __restrict__ feat, float* __restrict__ cnt, float* __restrict__ conf_acc)
{
    const int token = blockIdx.x;
    const int b = token >> 11;
    const int tid = threadIdx.x;

    float lx = loc[token * 2 + 0];
    float ly = loc[token * 2 + 1];
    lx = fminf(fmaxf(lx, -1.0f), 1.0f);
    ly = fminf(fmaxf(ly, -1.0f), 1.0f);
    const float pxf = rintf(0.5f * (lx + 1.0f) * 32.0f - 0.5f);   // round-half-even
    const float pyf = rintf(0.5f * (ly + 1.0f) * 32.0f - 0.5f);
    int x0 = (int)pxf; x0 = min(max(x0, 0), 31);
    int y0 = (int)pyf; y0 = min(max(y0, 0), 31);
    const int row = b * GM + y0 * 32 + x0;

    const float* s = src_tok + (size_t)token * CC;
    float* d = feat + (size_t)row * CC;
    atomicAdd(&d[tid],       s[tid]);
    atomicAdd(&d[tid + 256], s[tid + 256]);
    if (tid == 0) {
        atomicAdd(&cnt[row], 1.0f);
        atomicAdd(&conf_acc[row], conf_src[token]);
    }
}

// ---------------------------------------------------------------------------
// normalize: featb = bf16(feat/(cnt+1e-6) * (cnt>0)); conf likewise (in-place fp32)
// ---------------------------------------------------------------------------
__global__ __launch_bounds__(256) void normalize_kernel(const float* __restrict__ feat,
    const float* __restrict__ cnt, float* __restrict__ conf_acc, u16* __restrict__ featb)
{
    const int row = blockIdx.x;
    const int tid = threadIdx.x;
    const float cn = cnt[row];
    const float sc = (cn > 0.0f) ? (1.0f / (cn + 1e-6f)) : 0.0f;
    const float* f = feat + (size_t)row * CC;
    u16* o = featb + (size_t)row * CC;
    o[tid]       = f2bf(f[tid] * sc);
    o[tid + 256] = f2bf(f[tid + 256] * sc);
    if (tid == 0) conf_acc[row] *= sc;
}

// ---------------------------------------------------------------------------
// bf16 MFMA GEMM: C[M][Nn] = A[M][K] @ Bw[Nn][K]^T (+bias), fp32 or bf16 out.
// 128x128 tile, BK=32, 4 waves (2x2), global_load_lds w=16, XOR-swizzled LDS.
// LDS layout: row*64B + slot*16B, slot = kgroup ^ ((row>>2)&3)  (2-way = free)
// ---------------------------------------------------------------------------
template<bool BIAS, bool OUTBF>
__global__ __launch_bounds__(256) void gemm_mfma(const u16* __restrict__ A,
    const u16* __restrict__ Bw, const float* __restrict__ bias,
    float* __restrict__ Cf, u16* __restrict__ Cb, int M, int Nn, int K)
{
    __shared__ u16 As[4096];   // 128 rows x 32 k (8KB)
    __shared__ u16 Bs[4096];
    const int tid = threadIdx.x;
    const int l = tid & 63, r = l & 15, g = l >> 4;
    const int w = tid >> 6, wm = w >> 1, wn = w & 1;
    const int m0 = blockIdx.y * 128, n0 = blockIdx.x * 128;

    f32x4 acc[4][4] = {};

    const int nkt = K >> 5;
    for (int kt = 0; kt < nkt; ++kt) {
        __syncthreads();
        #pragma unroll
        for (int it = 0; it < 2; ++it) {
            const int c = it * 256 + tid;
            const int row = c >> 2;
            const int gg = (c & 3) ^ ((row >> 2) & 3);   // inverse-swizzled source
            const u16* ga = A  + (size_t)(m0 + row) * K + kt * 32 + gg * 8;
            const u16* gb = Bw + (size_t)(n0 + row) * K + kt * 32 + gg * 8;
            u16* la = (u16*)((char*)As + it * 4096 + (tid & 192) * 16);  // wave-uniform
            u16* lb = (u16*)((char*)Bs + it * 4096 + (tid & 192) * 16);
            __builtin_amdgcn_global_load_lds(ga, la, 16, 0, 0);
            __builtin_amdgcn_global_load_lds(gb, lb, 16, 0, 0);
        }
        __syncthreads();

        short8 af[4], bf[4];
        #pragma unroll
        for (int mi = 0; mi < 4; ++mi) {
            const int row = wm * 64 + mi * 16 + r;
            af[mi] = *(const short8*)((char*)As + row * 64 + ((g ^ (r >> 2)) & 3) * 16);
        }
        #pragma unroll
        for (int ni = 0; ni < 4; ++ni) {
            const int row = wn * 64 + ni * 16 + r;
            bf[ni] = *(const short8*)((char*)Bs + row * 64 + ((g ^ (r >> 2)) & 3) * 16);
        }
        #pragma unroll
        for (int mi = 0; mi < 4; ++mi)
            #pragma unroll
            for (int ni = 0; ni < 4; ++ni)
                acc[mi][ni] = __builtin_amdgcn_mfma_f32_16x16x32_bf16(af[mi], bf[ni], acc[mi][ni], 0, 0, 0);
    }

    #pragma unroll
    for (int mi = 0; mi < 4; ++mi) {
        const int rbase = m0 + wm * 64 + mi * 16 + g * 4;   // C/D: row=(l>>4)*4+reg
        #pragma unroll
        for (int ni = 0; ni < 4; ++ni) {
            const int col = n0 + wn * 64 + ni * 16 + r;     // C/D: col=lane&15
            const float bv = BIAS ? bias[col] : 0.0f;
            #pragma unroll
            for (int reg = 0; reg < 4; ++reg) {
                const float v = acc[mi][ni][reg] + bv;
                if (OUTBF) Cb[(size_t)(rbase + reg) * Nn + col] = f2bf(v);
                else       Cf[(size_t)(rbase + reg) * Nn + col] = v;
            }
        }
    }
}

// ---------------------------------------------------------------------------
// LayerNorm + exact GELU (fp32 in, bf16 out), one block per row of 512
// ---------------------------------------------------------------------------
__global__ __launch_bounds__(256) void ln_gelu_kernel(const float* __restrict__ xs,
    u16* __restrict__ xsb, const float* __restrict__ g, const float* __restrict__ bta)
{
    const int row = blockIdx.x;
    const int tid = threadIdx.x;
    const float2 v = *(const float2*)&xs[(size_t)row * CC + tid * 2];
    float s  = v.x + v.y;
    float ss = v.x * v.x + v.y * v.y;
    #pragma unroll
    for (int o = 32; o > 0; o >>= 1) { s += __shfl_down(s, o); ss += __shfl_down(ss, o); }
    __shared__ float red[10];
    const int wid = tid >> 6;
    if ((tid & 63) == 0) { red[wid] = s; red[4 + wid] = ss; }
    __syncthreads();
    if (tid == 0) {
        const float S  = red[0] + red[1] + red[2] + red[3];
        const float SS = red[4] + red[5] + red[6] + red[7];
        const float mu = S * (1.0f / 512.0f);
        const float var = SS * (1.0f / 512.0f) - mu * mu;
        red[8] = mu;
        red[9] = 1.0f / sqrtf(var + 1e-5f);
    }
    __syncthreads();
    const float mu = red[8], inv = red[9];
    const float2 gg = *(const float2*)&g[tid * 2];
    const float2 bb = *(const float2*)&bta[tid * 2];
    float x0 = (v.x - mu) * inv * gg.x + bb.x;
    float x1 = (v.y - mu) * inv * gg.y + bb.y;
    x0 = 0.5f * x0 * (1.0f + erff(x0 * 0.70710678118654752f));
    x1 = 0.5f * x1 * (1.0f + erff(x1 * 0.70710678118654752f));
    ushort2 o; o.x = f2bf(x0); o.y = f2bf(x1);
    *(ushort2*)&xsb[(size_t)row * CC + tid * 2] = o;
}

// ---------------------------------------------------------------------------
// MFMA flash attention. Block = 64 q-rows x (b,h); 4 waves x 16 rows each.
// K staged swizzled via global_load_lds; V transposed-on-store; P via LDS bf16.
// logits = qk*0.125 + conf[key]; online softmax in fp32, wave-parallel.
// ---------------------------------------------------------------------------
__global__ __launch_bounds__(256) void attn_mfma(const u16* __restrict__ q,
    const u16* __restrict__ kv, const float* __restrict__ conf, u16* __restrict__ out)
{
    const int qt = blockIdx.x;              // 0..31
    const int bh = blockIdx.y;              // 0..63
    const int b = bh >> 3, h = bh & 7;
    const int tid = threadIdx.x;
    const int l = tid & 63, r = l & 15, g = l >> 4;
    const int w = tid >> 6;

    __shared__ u16 Kl[4096];                // 64 keys x 64 dims (8KB), swizzled
    __shared__ u16 Vt[4096];                // 64 dims x 64 keys (8KB), swizzled
    __shared__ u16 Pl[4096];                // 4 waves x 16 rows x 64 keys (8KB)

    // Q fragments (kept in registers across key loop)
    short8 qf[2];
    {
        const u16* qp = q + ((size_t)(b * NN + qt * 64 + w * 16 + r)) * CC + h * HD + g * 8;
        qf[0] = *(const short8*)(qp);
        qf[1] = *(const short8*)(qp + 32);
    }

    f32x4 o[4] = {};
    float m_run[4], l_run[4];
    #pragma unroll
    for (int i = 0; i < 4; ++i) { m_run[i] = -1e30f; l_run[i] = 0.0f; }

    for (int kt = 0; kt < 16; ++kt) {
        __syncthreads();
        // stage K tile (swizzled source -> linear LDS dest)
        #pragma unroll
        for (int it = 0; it < 2; ++it) {
            const int c = it * 256 + tid;
            const int row = c >> 3, s = c & 7;
            const int gg = s ^ (row & 7);
            const u16* gp = kv + ((size_t)(b * GM + kt * 64 + row)) * 1024 + h * HD + gg * 8;
            __builtin_amdgcn_global_load_lds(gp,
                (u16*)((char*)Kl + it * 4096 + (tid & 192) * 16), 16, 0, 0);
        }
        // stage V transposed: Vt[dim][key], swizzled
        #pragma unroll
        for (int it = 0; it < 4; ++it) {
            const int flat = it * 256 + tid;
            const int tok = flat >> 4, dg = (flat & 15) * 4;
            const u16* vp = kv + ((size_t)(b * GM + kt * 64 + tok)) * 1024 + 512 + h * HD + dg;
            const ushort4 vv = *(const ushort4*)vp;
            const u16 ve[4] = {vv.x, vv.y, vv.z, vv.w};
            #pragma unroll
            for (int j = 0; j < 4; ++j) {
                const int d = dg + j;
                const int off = d * 128 + (((tok >> 3) ^ (d & 7)) * 16) + (tok & 7) * 2;
                *(u16*)((char*)Vt + off) = ve[j];
            }
        }
        __syncthreads();

        // ---- QK^T ----
        f32x4 s4[4] = {};
        #pragma unroll
        for (int ks = 0; ks < 2; ++ks)
            #pragma unroll
            for (int jt = 0; jt < 4; ++jt) {
                const int key = jt * 16 + r;
                const short8 kf = *(const short8*)((char*)Kl + key * 128 +
                                                   (((ks * 4 + g) ^ (key & 7)) * 16));
                s4[jt] = __builtin_amdgcn_mfma_f32_16x16x32_bf16(qf[ks], kf, s4[jt], 0, 0, 0);
            }

        // ---- online softmax (rows (l>>4)*4+reg; reduce over 16-lane groups) ----
        float conf_r[4];
        #pragma unroll
        for (int jt = 0; jt < 4; ++jt) conf_r[jt] = conf[b * GM + kt * 64 + jt * 16 + r];

        float L[4][4], mt[4];
        #pragma unroll
        for (int reg = 0; reg < 4; ++reg) {
            float mm = m_run[reg];
            #pragma unroll
            for (int jt = 0; jt < 4; ++jt) {
                L[reg][jt] = s4[jt][reg] * 0.125f + conf_r[jt];
                mm = fmaxf(mm, L[reg][jt]);
            }
            mt[reg] = mm;
        }
        #pragma unroll
        for (int m = 1; m < 16; m <<= 1)
            #pragma unroll
            for (int reg = 0; reg < 4; ++reg)
                mt[reg] = fmaxf(mt[reg], __shfl_xor(mt[reg], m, 64));

        float rf[4], ps[4];
        #pragma unroll
        for (int reg = 0; reg < 4; ++reg) { rf[reg] = __expf(m_run[reg] - mt[reg]); ps[reg] = 0.0f; }

        #pragma unroll
        for (int reg = 0; reg < 4; ++reg) {
            const int prow = g * 4 + reg;
            #pragma unroll
            for (int jt = 0; jt < 4; ++jt) {
                const float e = __expf(L[reg][jt] - mt[reg]);
                ps[reg] += e;
                const int col = jt * 16 + r;
                const int off = prow * 128 + (((col >> 3) ^ (prow & 7)) * 16) + (col & 7) * 2;
                *(u16*)((char*)Pl + w * 2048 + off) = f2bf(e);
            }
        }
        #pragma unroll
        for (int m = 1; m < 16; m <<= 1)
            #pragma unroll
            for (int reg = 0; reg < 4; ++reg)
                ps[reg] += __shfl_xor(ps[reg], m, 64);

        #pragma unroll
        for (int reg = 0; reg < 4; ++reg) {
            l_run[reg] = l_run[reg] * rf[reg] + ps[reg];
            m_run[reg] = mt[reg];
        }
        #pragma unroll
        for (int ni = 0; ni < 4; ++ni)
            #pragma unroll
            for (int reg = 0; reg < 4; ++reg)
                o[ni][reg] *= rf[reg];

        // ---- PV ----
        #pragma unroll
        for (int ks = 0; ks < 2; ++ks) {
            const short8 pa = *(const short8*)((char*)Pl + w * 2048 + r * 128 +
                                               (((ks * 4 + g) ^ (r & 7)) * 16));
            #pragma unroll
            for (int ni = 0; ni < 4; ++ni) {
                const int d = ni * 16 + r;
                const short8 vf = *(const short8*)((char*)Vt + d * 128 +
                                                   (((ks * 4 + g) ^ (d & 7)) * 16));
                o[ni] = __builtin_amdgcn_mfma_f32_16x16x32_bf16(pa, vf, o[ni], 0, 0, 0);
            }
        }
    }

    // epilogue: divide by l and store bf16
    const size_t orow = (size_t)(b * NN + qt * 64 + w * 16 + g * 4);
    #pragma unroll
    for (int ni = 0; ni < 4; ++ni)
        #pragma unroll
        for (int reg = 0; reg < 4; ++reg) {
            const float v = o[ni][reg] / l_run[reg];
            out[(orow + reg) * CC + h * HD + ni * 16 + r] = f2bf(v);
        }
}

// ---------------------------------------------------------------------------
extern "C" void kernel_launch(void* const* d_in, const int* in_sizes, int n_in,
                              void* d_out, int out_size, void* d_ws, size_t ws_size,
                              hipStream_t stream)
{
    (void)in_sizes; (void)n_in; (void)out_size; (void)ws_size;
    const float* x        = (const float*)d_in[0];
    const float* x_source = (const float*)d_in[1];
    const float* loc      = (const float*)d_in[2];
    const float* conf_src = (const float*)d_in[3];
    const float* q_w      = (const float*)d_in[4];
    const float* kv_w     = (const float*)d_in[5];
    const float* sr_w     = (const float*)d_in[6];
    const float* sr_b     = (const float*)d_in[7];
    const float* ln_g     = (const float*)d_in[8];
    const float* ln_b     = (const float*)d_in[9];
    const float* proj_w   = (const float*)d_in[10];
    const float* proj_b   = (const float*)d_in[11];

    char* ws = (char*)d_ws;
    float* feat    = (float*)(ws + B_FEATF);
    float* xs      = (float*)(ws + B_XSF);
    float* cnt     = (float*)(ws + B_CNT);
    float* conf    = (float*)(ws + B_CONF);
    u16*   x_bf    = (u16*)(ws + B_XBF);
    u16*   kv_bf   = (u16*)(ws + B_KVBF);
    u16*   feat_bf = (u16*)(ws + B_FEATBF);
    u16*   xs_bf   = (u16*)(ws + B_XSBF);
    u16*   wq_bf   = (u16*)(ws + B_WQ);
    u16*   wkv_bf  = (u16*)(ws + B_WKV);
    u16*   wsr_bf  = (u16*)(ws + B_WSR);
    u16*   wpr_bf  = (u16*)(ws + B_WPROJ);
    u16*   q_bf    = (u16*)(ws + B_XSF);    // reuse xs fp32 (dead after ln_gelu)
    u16*   attn_bf = (u16*)(ws + B_FEATF);  // reuse feat fp32 (dead after normalize)
    float* outp    = (float*)d_out;

    hipMemsetAsync(feat, 0, (size_t)8192 * 512 * sizeof(float), stream);
    hipMemsetAsync(cnt,  0, (size_t)16384 * sizeof(float), stream);   // cnt+conf contiguous

    // casts to bf16
    cast_bf16_kernel<<<8192, 256, 0, stream>>>(x, x_bf);            // 16384*512
    cast_bf16_kernel<<<256,  256, 0, stream>>>(q_w, wq_bf);         // 512*512
    cast_bf16_kernel<<<512,  256, 0, stream>>>(kv_w, wkv_bf);       // 1024*512
    cast_bf16_kernel<<<256,  256, 0, stream>>>(sr_w, wsr_bf);
    cast_bf16_kernel<<<256,  256, 0, stream>>>(proj_w, wpr_bf);

    // token2map
    scatter_kernel<<<BB * 2048, 256, 0, stream>>>(x_source, loc, conf_src, feat, cnt, conf);
    normalize_kernel<<<8192, 256, 0, stream>>>(feat, cnt, conf, feat_bf);

    // xs = feat @ sr_w^T + sr_b   (fp32 out for exact LN)
    gemm_mfma<true, false><<<dim3(4, 64), 256, 0, stream>>>(feat_bf, wsr_bf, sr_b, xs, nullptr, 8192, 512, 512);
    ln_gelu_kernel<<<8192, 256, 0, stream>>>(xs, xs_bf, ln_g, ln_b);

    // kv = xs @ kv_w^T  (bf16 out)
    gemm_mfma<false, true><<<dim3(8, 64), 256, 0, stream>>>(xs_bf, wkv_bf, nullptr, nullptr, kv_bf, 8192, 1024, 512);

    // q = x @ q_w^T  (bf16 out, into old xs region)
    gemm_mfma<false, true><<<dim3(4, 128), 256, 0, stream>>>(x_bf, wq_bf, nullptr, nullptr, q_bf, 16384, 512, 512);

    // attention -> bf16 (into old feat region)
    attn_mfma<<<dim3(32, 64), 256, 0, stream>>>(q_bf, kv_bf, conf, attn_bf);

    // out = attn @ proj_w^T + proj_b  (fp32 out)
    gemm_mfma<true, false><<<dim3(4, 128), 256, 0, stream>>>(attn_bf, wpr_bf, proj_b, outp, nullptr, 16384, 512, 512);
}

// Round 3
// 416.211 us; speedup vs baseline: 1.0215x; 1.0215x over previous
//
#include <hip/hip_runtime.h>
#include <math.h>

typedef unsigned short u16;
typedef __attribute__((ext_vector_type(8))) short short8;
typedef __attribute__((ext_vector_type(4))) float f32x4;

// Problem constants (B=8, N=2048, Nsrc=2048, C=512, H=W=64, sr_ratio=2 -> 32x32 grid)
#define BB     8
#define NN     2048
#define CC     512
#define HEADS  8
#define HD     64
#define GM     1024   // 32*32 spatial tokens per batch

// Workspace byte offsets (total ~82.6 MB)
#define B_FEATF   ((size_t)0)                    // feat fp32 16MB; later attn_bf (16MB)
#define B_XSF     ((size_t)16*1024*1024)         // xs fp32 16MB; later q_bf (16MB)
#define B_XBF     ((size_t)32*1024*1024)         // x bf16 16MB
#define B_KB      ((size_t)48*1024*1024)         // K bf16 [8192][512] 8MB
#define B_VT      ((size_t)56*1024*1024)         // V^T bf16 [b][h][64][1024] 8MB
#define B_FEATBF  ((size_t)64*1024*1024)         // feat bf16 8MB
#define B_XSBF    ((size_t)72*1024*1024)         // xs bf16 8MB
#define B_CNT     ((size_t)80*1024*1024)         // 32KB
#define B_CONF    (B_CNT + (size_t)32*1024)      // 32KB
#define B_WQ      (B_CNT + (size_t)64*1024)      // 512KB
#define B_WKV     (B_WQ  + (size_t)512*1024)     // 1MB
#define B_WSR     (B_WKV + (size_t)1024*1024)    // 512KB
#define B_WPROJ   (B_WSR + (size_t)512*1024)     // 512KB

__device__ __forceinline__ u16 f2bf(float f) {
    unsigned u = __float_as_uint(f);
    unsigned r = (u + 0x7fffu + ((u >> 16) & 1u)) >> 16;   // RNE
    return (u16)r;
}

// ---------------------------------------------------------------------------
// fp32 -> bf16 cast (grid*256 float4-quads)
// ---------------------------------------------------------------------------
__global__ __launch_bounds__(256) void cast_bf16_kernel(const float* __restrict__ in,
                                                        u16* __restrict__ out)
{
    const int i = blockIdx.x * 256 + threadIdx.x;
    const float4 v = ((const float4*)in)[i];
    ushort4 o;
    o.x = f2bf(v.x); o.y = f2bf(v.y); o.z = f2bf(v.z); o.w = f2bf(v.w);
    ((ushort4*)out)[i] = o;
}

// ---------------------------------------------------------------------------
// token2map scatter: one block per source token (fp32 atomics, exact)
// ---------------------------------------------------------------------------
__global__ __launch_bounds__(256) void scatter_kernel(const float* __restrict__ src_tok,
    const float* __restrict__ loc, const float* __restrict__ conf_src,
    float* __restrict__ feat, float* __restrict__ cnt, float* __restrict__ conf_acc)
{
    const int token = blockIdx.x;
    const int b = token >> 11;
    const int tid = threadIdx.x;

    float lx = loc[token * 2 + 0];
    float ly = loc[token * 2 + 1];
    lx = fminf(fmaxf(lx, -1.0f), 1.0f);
    ly = fminf(fmaxf(ly, -1.0f), 1.0f);
    const float pxf = rintf(0.5f * (lx + 1.0f) * 32.0f - 0.5f);   // round-half-even
    const float pyf = rintf(0.5f * (ly + 1.0f) * 32.0f - 0.5f);
    int x0 = (int)pxf; x0 = min(max(x0, 0), 31);
    int y0 = (int)pyf; y0 = min(max(y0, 0), 31);
    const int row = b * GM + y0 * 32 + x0;

    const float* s = src_tok + (size_t)token * CC;
    float* d = feat + (size_t)row * CC;
    atomicAdd(&d[tid],       s[tid]);
    atomicAdd(&d[tid + 256], s[tid + 256]);
    if (tid == 0) {
        atomicAdd(&cnt[row], 1.0f);
        atomicAdd(&conf_acc[row], conf_src[token]);
    }
}

// ---------------------------------------------------------------------------
// normalize: featb = bf16(feat/(cnt+1e-6) * (cnt>0)); conf likewise (in-place fp32)
// ---------------------------------------------------------------------------
__global__ __launch_bounds__(256) void normalize_kernel(const float* __restrict__ feat,
    const float* __restrict__ cnt, float* __restrict__ conf_acc, u16* __restrict__ featb)
{
    const int row = blockIdx.x;
    const int tid = threadIdx.x;
    const float cn = cnt[row];
    const float sc = (cn > 0.0f) ? (1.0f / (cn + 1e-6f)) : 0.0f;
    const float* f = feat + (size_t)row * CC;
    u16* o = featb + (size_t)row * CC;
    o[tid]       = f2bf(f[tid] * sc);
    o[tid + 256] = f2bf(f[tid + 256] * sc);
    if (tid == 0) conf_acc[row] *= sc;
}

// ---------------------------------------------------------------------------
// bf16 MFMA GEMM: C[M][Nn] = A[M][K] @ Bw[Nn][K]^T (+bias).
// 128x128 tile, BK=32, 4 waves (2x2), global_load_lds w=16, XOR-swizzled LDS.
// OUTMODE: 0 = fp32 out (Cf), 1 = bf16 out (Cb), 2 = V^T scatter-out (Vt):
//   rows are kv_w features (512 V-features), cols are tokens (b*1024+tok);
//   Vt[((b*8+head)*64+d)*1024 + tok], coalesced over lane (token) axis.
// ---------------------------------------------------------------------------
template<bool BIAS, int OUTMODE>
__global__ __launch_bounds__(256) void gemm_mfma(const u16* __restrict__ A,
    const u16* __restrict__ Bw, const float* __restrict__ bias,
    float* __restrict__ Cf, u16* __restrict__ Cb, u16* __restrict__ Vt,
    int M, int Nn, int K)
{
    __shared__ u16 As[4096];   // 128 rows x 32 k (8KB)
    __shared__ u16 Bs[4096];
    const int tid = threadIdx.x;
    const int l = tid & 63, r = l & 15, g = l >> 4;
    const int w = tid >> 6, wm = w >> 1, wn = w & 1;
    const int m0 = blockIdx.y * 128, n0 = blockIdx.x * 128;

    f32x4 acc[4][4] = {};

    const int nkt = K >> 5;
    for (int kt = 0; kt < nkt; ++kt) {
        __syncthreads();
        #pragma unroll
        for (int it = 0; it < 2; ++it) {
            const int c = it * 256 + tid;
            const int row = c >> 2;
            const int gg = (c & 3) ^ ((row >> 2) & 3);   // inverse-swizzled source
            const u16* ga = A  + (size_t)(m0 + row) * K + kt * 32 + gg * 8;
            const u16* gb = Bw + (size_t)(n0 + row) * K + kt * 32 + gg * 8;
            u16* la = (u16*)((char*)As + it * 4096 + (tid & 192) * 16);  // wave-uniform
            u16* lb = (u16*)((char*)Bs + it * 4096 + (tid & 192) * 16);
            __builtin_amdgcn_global_load_lds(ga, la, 16, 0, 0);
            __builtin_amdgcn_global_load_lds(gb, lb, 16, 0, 0);
        }
        __syncthreads();

        short8 af[4], bf[4];
        #pragma unroll
        for (int mi = 0; mi < 4; ++mi) {
            const int row = wm * 64 + mi * 16 + r;
            af[mi] = *(const short8*)((char*)As + row * 64 + ((g ^ (r >> 2)) & 3) * 16);
        }
        #pragma unroll
        for (int ni = 0; ni < 4; ++ni) {
            const int row = wn * 64 + ni * 16 + r;
            bf[ni] = *(const short8*)((char*)Bs + row * 64 + ((g ^ (r >> 2)) & 3) * 16);
        }
        #pragma unroll
        for (int mi = 0; mi < 4; ++mi)
            #pragma unroll
            for (int ni = 0; ni < 4; ++ni)
                acc[mi][ni] = __builtin_amdgcn_mfma_f32_16x16x32_bf16(af[mi], bf[ni], acc[mi][ni], 0, 0, 0);
    }

    #pragma unroll
    for (int mi = 0; mi < 4; ++mi) {
        const int rbase = m0 + wm * 64 + mi * 16 + g * 4;   // C/D: row=(l>>4)*4+reg
        #pragma unroll
        for (int ni = 0; ni < 4; ++ni) {
            const int col = n0 + wn * 64 + ni * 16 + r;     // C/D: col=lane&15
            const float bv = BIAS ? bias[col] : 0.0f;
            #pragma unroll
            for (int reg = 0; reg < 4; ++reg) {
                const float v = acc[mi][ni][reg] + bv;
                if (OUTMODE == 0) {
                    Cf[(size_t)(rbase + reg) * Nn + col] = v;
                } else if (OUTMODE == 1) {
                    Cb[(size_t)(rbase + reg) * Nn + col] = f2bf(v);
                } else {
                    const int f = rbase + reg;              // V feature 0..511
                    const int head = f >> 6, d = f & 63;
                    const int bb2 = col >> 10, tok = col & 1023;
                    Vt[(((size_t)bb2 * 8 + head) * 64 + d) * 1024 + tok] = f2bf(v);
                }
            }
        }
    }
}

// ---------------------------------------------------------------------------
// LayerNorm + exact GELU (fp32 in, bf16 out), one block per row of 512
// ---------------------------------------------------------------------------
__global__ __launch_bounds__(256) void ln_gelu_kernel(const float* __restrict__ xs,
    u16* __restrict__ xsb, const float* __restrict__ g, const float* __restrict__ bta)
{
    const int row = blockIdx.x;
    const int tid = threadIdx.x;
    const float2 v = *(const float2*)&xs[(size_t)row * CC + tid * 2];
    float s  = v.x + v.y;
    float ss = v.x * v.x + v.y * v.y;
    #pragma unroll
    for (int o = 32; o > 0; o >>= 1) { s += __shfl_down(s, o); ss += __shfl_down(ss, o); }
    __shared__ float red[10];
    const int wid = tid >> 6;
    if ((tid & 63) == 0) { red[wid] = s; red[4 + wid] = ss; }
    __syncthreads();
    if (tid == 0) {
        const float S  = red[0] + red[1] + red[2] + red[3];
        const float SS = red[4] + red[5] + red[6] + red[7];
        const float mu = S * (1.0f / 512.0f);
        const float var = SS * (1.0f / 512.0f) - mu * mu;
        red[8] = mu;
        red[9] = 1.0f / sqrtf(var + 1e-5f);
    }
    __syncthreads();
    const float mu = red[8], inv = red[9];
    const float2 gg = *(const float2*)&g[tid * 2];
    const float2 bb = *(const float2*)&bta[tid * 2];
    float x0 = (v.x - mu) * inv * gg.x + bb.x;
    float x1 = (v.y - mu) * inv * gg.y + bb.y;
    x0 = 0.5f * x0 * (1.0f + erff(x0 * 0.70710678118654752f));
    x1 = 0.5f * x1 * (1.0f + erff(x1 * 0.70710678118654752f));
    ushort2 o; o.x = f2bf(x0); o.y = f2bf(x1);
    *(ushort2*)&xsb[(size_t)row * CC + tid * 2] = o;
}

// ---------------------------------------------------------------------------
// MFMA flash attention v2. Block = 64 q-rows x (b,h); 4 waves x 16 rows.
// K staged swizzled via global_load_lds (8KB); V^T read directly from L2
// (no in-kernel transpose); P via per-wave swizzled LDS bf16 (8KB);
// conf staged once (4KB). logits = qk*0.125 + conf[key]; online softmax fp32.
// ---------------------------------------------------------------------------
__global__ __launch_bounds__(256) void attn_mfma(const u16* __restrict__ q,
    const u16* __restrict__ kb, const u16* __restrict__ vt,
    const float* __restrict__ conf, u16* __restrict__ out)
{
    const int qt = blockIdx.x;              // 0..31
    const int bh = blockIdx.y;              // 0..63
    const int b = bh >> 3, h = bh & 7;
    const int tid = threadIdx.x;
    const int l = tid & 63, r = l & 15, g = l >> 4;
    const int w = tid >> 6;

    __shared__ u16 Kl[4096];                // 64 keys x 64 dims (8KB), swizzled
    __shared__ u16 Pl[4096];                // 4 waves x 16 rows x 64 keys (8KB)
    __shared__ float confs[1024];           // per-block conf cache (4KB)

    #pragma unroll
    for (int cc = 0; cc < 4; ++cc)
        confs[tid + cc * 256] = conf[b * GM + cc * 256 + tid];

    // Q fragments (kept in registers across key loop)
    short8 qf[2];
    {
        const u16* qp = q + ((size_t)(b * NN + qt * 64 + w * 16 + r)) * CC + h * HD + g * 8;
        qf[0] = *(const short8*)(qp);
        qf[1] = *(const short8*)(qp + 32);
    }

    const u16* vbase = vt + ((size_t)(b * 8 + h) * 64) * 1024;   // + d*1024 + key

    f32x4 o[4] = {};
    float m_run[4], l_run[4];
    #pragma unroll
    for (int i = 0; i < 4; ++i) { m_run[i] = -1e30f; l_run[i] = 0.0f; }

    for (int kt = 0; kt < 16; ++kt) {
        // prefetch V^T fragments for this tile (L2-resident; latency hides
        // under K-stage + QK^T + softmax)
        short8 vfr[2][4];
        #pragma unroll
        for (int ks = 0; ks < 2; ++ks)
            #pragma unroll
            for (int ni = 0; ni < 4; ++ni)
                vfr[ks][ni] = *(const short8*)(vbase + (size_t)(ni * 16 + r) * 1024
                                               + kt * 64 + ks * 32 + g * 8);

        __syncthreads();
        // stage K tile (inverse-swizzled source -> linear LDS dest)
        #pragma unroll
        for (int it = 0; it < 2; ++it) {
            const int c = it * 256 + tid;
            const int row = c >> 3, s = c & 7;
            const int gg = s ^ (row & 7);
            const u16* gp = kb + ((size_t)(b * GM + kt * 64 + row)) * 512 + h * HD + gg * 8;
            __builtin_amdgcn_global_load_lds(gp,
                (u16*)((char*)Kl + it * 4096 + (tid & 192) * 16), 16, 0, 0);
        }
        __syncthreads();

        // ---- QK^T ----
        f32x4 s4[4] = {};
        #pragma unroll
        for (int ks = 0; ks < 2; ++ks)
            #pragma unroll
            for (int jt = 0; jt < 4; ++jt) {
                const int key = jt * 16 + r;
                const short8 kf = *(const short8*)((char*)Kl + key * 128 +
                                                   (((ks * 4 + g) ^ (key & 7)) * 16));
                s4[jt] = __builtin_amdgcn_mfma_f32_16x16x32_bf16(qf[ks], kf, s4[jt], 0, 0, 0);
            }

        // ---- online softmax (rows (l>>4)*4+reg; reduce over 16-lane groups) ----
        float conf_r[4];
        #pragma unroll
        for (int jt = 0; jt < 4; ++jt) conf_r[jt] = confs[kt * 64 + jt * 16 + r];

        float L[4][4], mt[4];
        #pragma unroll
        for (int reg = 0; reg < 4; ++reg) {
            float mm = m_run[reg];
            #pragma unroll
            for (int jt = 0; jt < 4; ++jt) {
                L[reg][jt] = s4[jt][reg] * 0.125f + conf_r[jt];
                mm = fmaxf(mm, L[reg][jt]);
            }
            mt[reg] = mm;
        }
        #pragma unroll
        for (int m = 1; m < 16; m <<= 1)
            #pragma unroll
            for (int reg = 0; reg < 4; ++reg)
                mt[reg] = fmaxf(mt[reg], __shfl_xor(mt[reg], m, 64));

        float rf[4], ps[4];
        #pragma unroll
        for (int reg = 0; reg < 4; ++reg) { rf[reg] = __expf(m_run[reg] - mt[reg]); ps[reg] = 0.0f; }

        #pragma unroll
        for (int reg = 0; reg < 4; ++reg) {
            const int prow = g * 4 + reg;
            #pragma unroll
            for (int jt = 0; jt < 4; ++jt) {
                const float e = __expf(L[reg][jt] - mt[reg]);
                ps[reg] += e;
                const int col = jt * 16 + r;
                const int off = prow * 128 + (((col >> 3) ^ (prow & 7)) * 16) + (col & 7) * 2;
                *(u16*)((char*)Pl + w * 2048 + off) = f2bf(e);
            }
        }
        #pragma unroll
        for (int m = 1; m < 16; m <<= 1)
            #pragma unroll
            for (int reg = 0; reg < 4; ++reg)
                ps[reg] += __shfl_xor(ps[reg], m, 64);

        #pragma unroll
        for (int reg = 0; reg < 4; ++reg) {
            l_run[reg] = l_run[reg] * rf[reg] + ps[reg];
            m_run[reg] = mt[reg];
        }
        #pragma unroll
        for (int ni = 0; ni < 4; ++ni)
            #pragma unroll
            for (int reg = 0; reg < 4; ++reg)
                o[ni][reg] *= rf[reg];

        // ---- PV (P from per-wave LDS, V^T from registers) ----
        #pragma unroll
        for (int ks = 0; ks < 2; ++ks) {
            const short8 pa = *(const short8*)((char*)Pl + w * 2048 + r * 128 +
                                               (((ks * 4 + g) ^ (r & 7)) * 16));
            #pragma unroll
            for (int ni = 0; ni < 4; ++ni)
                o[ni] = __builtin_amdgcn_mfma_f32_16x16x32_bf16(pa, vfr[ks][ni], o[ni], 0, 0, 0);
        }
    }

    // epilogue: divide by l and store bf16
    const size_t orow = (size_t)(b * NN + qt * 64 + w * 16 + g * 4);
    #pragma unroll
    for (int ni = 0; ni < 4; ++ni)
        #pragma unroll
        for (int reg = 0; reg < 4; ++reg) {
            const float v = o[ni][reg] / l_run[reg];
            out[(orow + reg) * CC + h * HD + ni * 16 + r] = f2bf(v);
        }
}

// ---------------------------------------------------------------------------
extern "C" void kernel_launch(void* const* d_in, const int* in_sizes, int n_in,
                              void* d_out, int out_size, void* d_ws, size_t ws_size,
                              hipStream_t stream)
{
    (void)in_sizes; (void)n_in; (void)out_size; (void)ws_size;
    const float* x        = (const float*)d_in[0];
    const float* x_source = (const float*)d_in[1];
    const float* loc      = (const float*)d_in[2];
    const float* conf_src = (const float*)d_in[3];
    const float* q_w      = (const float*)d_in[4];
    const float* kv_w     = (const float*)d_in[5];
    const float* sr_w     = (const float*)d_in[6];
    const float* sr_b     = (const float*)d_in[7];
    const float* ln_g     = (const float*)d_in[8];
    const float* ln_b     = (const float*)d_in[9];
    const float* proj_w   = (const float*)d_in[10];
    const float* proj_b   = (const float*)d_in[11];

    char* ws = (char*)d_ws;
    float* feat    = (float*)(ws + B_FEATF);
    float* xs      = (float*)(ws + B_XSF);
    float* cnt     = (float*)(ws + B_CNT);
    float* conf    = (float*)(ws + B_CONF);
    u16*   x_bf    = (u16*)(ws + B_XBF);
    u16*   kb_bf   = (u16*)(ws + B_KB);
    u16*   vt_bf   = (u16*)(ws + B_VT);
    u16*   feat_bf = (u16*)(ws + B_FEATBF);
    u16*   xs_bf   = (u16*)(ws + B_XSBF);
    u16*   wq_bf   = (u16*)(ws + B_WQ);
    u16*   wkv_bf  = (u16*)(ws + B_WKV);
    u16*   wsr_bf  = (u16*)(ws + B_WSR);
    u16*   wpr_bf  = (u16*)(ws + B_WPROJ);
    u16*   q_bf    = (u16*)(ws + B_XSF);    // reuse xs fp32 (dead after ln_gelu)
    u16*   attn_bf = (u16*)(ws + B_FEATF);  // reuse feat fp32 (dead after normalize)
    float* outp    = (float*)d_out;

    hipMemsetAsync(feat, 0, (size_t)8192 * 512 * sizeof(float), stream);
    hipMemsetAsync(cnt,  0, (size_t)16384 * sizeof(float), stream);   // cnt+conf contiguous

    // casts to bf16
    cast_bf16_kernel<<<8192, 256, 0, stream>>>(x, x_bf);            // 16384*512
    cast_bf16_kernel<<<256,  256, 0, stream>>>(q_w, wq_bf);         // 512*512
    cast_bf16_kernel<<<512,  256, 0, stream>>>(kv_w, wkv_bf);       // 1024*512
    cast_bf16_kernel<<<256,  256, 0, stream>>>(sr_w, wsr_bf);
    cast_bf16_kernel<<<256,  256, 0, stream>>>(proj_w, wpr_bf);

    // token2map
    scatter_kernel<<<BB * 2048, 256, 0, stream>>>(x_source, loc, conf_src, feat, cnt, conf);
    normalize_kernel<<<8192, 256, 0, stream>>>(feat, cnt, conf, feat_bf);

    // xs = feat @ sr_w^T + sr_b   (fp32 out for exact LN)
    gemm_mfma<true, 0><<<dim3(4, 64), 256, 0, stream>>>(feat_bf, wsr_bf, sr_b, xs, nullptr, nullptr, 8192, 512, 512);
    ln_gelu_kernel<<<8192, 256, 0, stream>>>(xs, xs_bf, ln_g, ln_b);

    // K = xs @ Wk^T  (bf16 out, [8192][512])
    gemm_mfma<false, 1><<<dim3(4, 64), 256, 0, stream>>>(xs_bf, wkv_bf, nullptr, nullptr, kb_bf, nullptr, 8192, 512, 512);

    // V^T = Wv @ xs^T  (operand-swapped GEMM; transposed write via C/D lane layout)
    gemm_mfma<false, 2><<<dim3(64, 4), 256, 0, stream>>>(wkv_bf + (size_t)512 * 512, xs_bf, nullptr, nullptr, nullptr, vt_bf, 512, 8192, 512);

    // q = x @ q_w^T  (bf16 out, into old xs region)
    gemm_mfma<false, 1><<<dim3(4, 128), 256, 0, stream>>>(x_bf, wq_bf, nullptr, nullptr, q_bf, nullptr, 16384, 512, 512);

    // attention -> bf16 (into old feat region)
    attn_mfma<<<dim3(32, 64), 256, 0, stream>>>(q_bf, kb_bf, vt_bf, conf, attn_bf);

    // out = attn @ proj_w^T + proj_b  (fp32 out)
    gemm_mfma<true, 0><<<dim3(4, 128), 256, 0, stream>>>(attn_bf, wpr_bf, proj_b, outp, nullptr, nullptr, 16384, 512, 512);
}

// Round 4
// 407.562 us; speedup vs baseline: 1.0432x; 1.0212x over previous
//
#include <hip/hip_runtime.h>
#include <math.h>

typedef unsigned short u16;
typedef __attribute__((ext_vector_type(8))) short short8;
typedef __attribute__((ext_vector_type(4))) float f32x4;
typedef __attribute__((ext_vector_type(4))) int   i32x4;

// Problem constants (B=8, N=2048, Nsrc=2048, C=512, H=W=64, sr_ratio=2 -> 32x32 grid)
#define BB     8
#define NN     2048
#define CC     512
#define HEADS  8
#define HD     64
#define GM     1024   // 32*32 spatial tokens per batch

// Workspace byte offsets (total ~82.6 MB)
#define B_FEATF   ((size_t)0)                    // feat fp32 16MB; later attn_bf (16MB)
#define B_XSF     ((size_t)16*1024*1024)         // xs fp32 16MB; later q_bf (16MB)
#define B_XBF     ((size_t)32*1024*1024)         // x bf16 16MB
#define B_KB      ((size_t)48*1024*1024)         // K bf16 [8192][512] 8MB
#define B_VT      ((size_t)56*1024*1024)         // V^T bf16 [b][h][64][1024] 8MB (key-permuted)
#define B_FEATBF  ((size_t)64*1024*1024)         // feat bf16 8MB
#define B_XSBF    ((size_t)72*1024*1024)         // xs bf16 8MB
#define B_CNT     ((size_t)80*1024*1024)         // 32KB
#define B_CONF    (B_CNT + (size_t)32*1024)      // 32KB
#define B_WQ      (B_CNT + (size_t)64*1024)      // 512KB
#define B_WKV     (B_WQ  + (size_t)512*1024)     // 1MB
#define B_WSR     (B_WKV + (size_t)1024*1024)    // 512KB
#define B_WPROJ   (B_WSR + (size_t)512*1024)     // 512KB

__device__ __forceinline__ u16 f2bf(float f) {
    unsigned u = __float_as_uint(f);
    unsigned r = (u + 0x7fffu + ((u >> 16) & 1u)) >> 16;   // RNE
    return (u16)r;
}

__device__ __forceinline__ unsigned cvt_pk_bf16(float lo, float hi) {
    unsigned r;
    asm("v_cvt_pk_bf16_f32 %0, %1, %2" : "=v"(r) : "v"(lo), "v"(hi));
    return r;
}

// ---------------------------------------------------------------------------
// fp32 -> bf16 cast (grid*256 float4-quads)
// ---------------------------------------------------------------------------
__global__ __launch_bounds__(256) void cast_bf16_kernel(const float* __restrict__ in,
                                                        u16* __restrict__ out)
{
    const int i = blockIdx.x * 256 + threadIdx.x;
    const float4 v = ((const float4*)in)[i];
    ushort4 o;
    o.x = f2bf(v.x); o.y = f2bf(v.y); o.z = f2bf(v.z); o.w = f2bf(v.w);
    ((ushort4*)out)[i] = o;
}

// ---------------------------------------------------------------------------
// token2map scatter: one block per source token (fp32 atomics, exact)
// ---------------------------------------------------------------------------
__global__ __launch_bounds__(256) void scatter_kernel(const float* __restrict__ src_tok,
    const float* __restrict__ loc, const float* __restrict__ conf_src,
    float* __restrict__ feat, float* __restrict__ cnt, float* __restrict__ conf_acc)
{
    const int token = blockIdx.x;
    const int b = token >> 11;
    const int tid = threadIdx.x;

    float lx = loc[token * 2 + 0];
    float ly = loc[token * 2 + 1];
    lx = fminf(fmaxf(lx, -1.0f), 1.0f);
    ly = fminf(fmaxf(ly, -1.0f), 1.0f);
    const float pxf = rintf(0.5f * (lx + 1.0f) * 32.0f - 0.5f);   // round-half-even
    const float pyf = rintf(0.5f * (ly + 1.0f) * 32.0f - 0.5f);
    int x0 = (int)pxf; x0 = min(max(x0, 0), 31);
    int y0 = (int)pyf; y0 = min(max(y0, 0), 31);
    const int row = b * GM + y0 * 32 + x0;

    const float* s = src_tok + (size_t)token * CC;
    float* d = feat + (size_t)row * CC;
    atomicAdd(&d[tid],       s[tid]);
    atomicAdd(&d[tid + 256], s[tid + 256]);
    if (tid == 0) {
        atomicAdd(&cnt[row], 1.0f);
        atomicAdd(&conf_acc[row], conf_src[token]);
    }
}

// ---------------------------------------------------------------------------
// normalize: featb = bf16(feat/(cnt+1e-6) * (cnt>0)); conf likewise (in-place fp32)
// ---------------------------------------------------------------------------
__global__ __launch_bounds__(256) void normalize_kernel(const float* __restrict__ feat,
    const float* __restrict__ cnt, float* __restrict__ conf_acc, u16* __restrict__ featb)
{
    const int row = blockIdx.x;
    const int tid = threadIdx.x;
    const float cn = cnt[row];
    const float sc = (cn > 0.0f) ? (1.0f / (cn + 1e-6f)) : 0.0f;
    const float* f = feat + (size_t)row * CC;
    u16* o = featb + (size_t)row * CC;
    o[tid]       = f2bf(f[tid] * sc);
    o[tid + 256] = f2bf(f[tid + 256] * sc);
    if (tid == 0) conf_acc[row] *= sc;
}

// ---------------------------------------------------------------------------
// bf16 MFMA GEMM: C[M][Nn] = A[M][K] @ Bw[Nn][K]^T (+bias).
// 128x128 tile, BK=32, 4 waves (2x2), global_load_lds w=16, XOR-swizzled LDS.
// OUTMODE: 0 = fp32 out (Cf), 1 = bf16 out (Cb), 2 = V^T scatter-out (Vt):
//   rows are kv_w features (512 V-features), cols are tokens (b*1024+tok).
//   Token axis is PERMUTED within each 64-token tile so attention's PV
//   A-fragment (packed P registers) lines up slot-for-slot with V^T:
//   S(u) = 32*(u>>5) | 8*((u>>2)&3) | 4*((u>>4)&1) | (u&3).
// ---------------------------------------------------------------------------
template<bool BIAS, int OUTMODE>
__global__ __launch_bounds__(256) void gemm_mfma(const u16* __restrict__ A,
    const u16* __restrict__ Bw, const float* __restrict__ bias,
    float* __restrict__ Cf, u16* __restrict__ Cb, u16* __restrict__ Vt,
    int M, int Nn, int K)
{
    __shared__ u16 As[4096];   // 128 rows x 32 k (8KB)
    __shared__ u16 Bs[4096];
    const int tid = threadIdx.x;
    const int l = tid & 63, r = l & 15, g = l >> 4;
    const int w = tid >> 6, wm = w >> 1, wn = w & 1;
    const int m0 = blockIdx.y * 128, n0 = blockIdx.x * 128;

    f32x4 acc[4][4] = {};

    const int nkt = K >> 5;
    for (int kt = 0; kt < nkt; ++kt) {
        __syncthreads();
        #pragma unroll
        for (int it = 0; it < 2; ++it) {
            const int c = it * 256 + tid;
            const int row = c >> 2;
            const int gg = (c & 3) ^ ((row >> 2) & 3);   // inverse-swizzled source
            const u16* ga = A  + (size_t)(m0 + row) * K + kt * 32 + gg * 8;
            const u16* gb = Bw + (size_t)(n0 + row) * K + kt * 32 + gg * 8;
            u16* la = (u16*)((char*)As + it * 4096 + (tid & 192) * 16);  // wave-uniform
            u16* lb = (u16*)((char*)Bs + it * 4096 + (tid & 192) * 16);
            __builtin_amdgcn_global_load_lds(ga, la, 16, 0, 0);
            __builtin_amdgcn_global_load_lds(gb, lb, 16, 0, 0);
        }
        __syncthreads();

        short8 af[4], bf[4];
        #pragma unroll
        for (int mi = 0; mi < 4; ++mi) {
            const int row = wm * 64 + mi * 16 + r;
            af[mi] = *(const short8*)((char*)As + row * 64 + ((g ^ (r >> 2)) & 3) * 16);
        }
        #pragma unroll
        for (int ni = 0; ni < 4; ++ni) {
            const int row = wn * 64 + ni * 16 + r;
            bf[ni] = *(const short8*)((char*)Bs + row * 64 + ((g ^ (r >> 2)) & 3) * 16);
        }
        #pragma unroll
        for (int mi = 0; mi < 4; ++mi)
            #pragma unroll
            for (int ni = 0; ni < 4; ++ni)
                acc[mi][ni] = __builtin_amdgcn_mfma_f32_16x16x32_bf16(af[mi], bf[ni], acc[mi][ni], 0, 0, 0);
    }

    #pragma unroll
    for (int mi = 0; mi < 4; ++mi) {
        const int rbase = m0 + wm * 64 + mi * 16 + g * 4;   // C/D: row=(l>>4)*4+reg
        #pragma unroll
        for (int ni = 0; ni < 4; ++ni) {
            const int col = n0 + wn * 64 + ni * 16 + r;     // C/D: col=lane&15
            const float bv = BIAS ? bias[col] : 0.0f;
            #pragma unroll
            for (int reg = 0; reg < 4; ++reg) {
                const float v = acc[mi][ni][reg] + bv;
                if (OUTMODE == 0) {
                    Cf[(size_t)(rbase + reg) * Nn + col] = v;
                } else if (OUTMODE == 1) {
                    Cb[(size_t)(rbase + reg) * Nn + col] = f2bf(v);
                } else {
                    const int f = rbase + reg;              // V feature 0..511
                    const int head = f >> 6, d = f & 63;
                    const int bb2 = col >> 10, tok = col & 1023;
                    const int u = tok & 63;
                    const int S = ((u >> 5) << 5) | (((u >> 2) & 3) << 3)
                                | (((u >> 4) & 1) << 2) | (u & 3);
                    const int stok = (tok & ~63) | S;
                    Vt[(((size_t)bb2 * 8 + head) * 64 + d) * 1024 + stok] = f2bf(v);
                }
            }
        }
    }
}

// ---------------------------------------------------------------------------
// LayerNorm + exact GELU (fp32 in, bf16 out), one block per row of 512
// ---------------------------------------------------------------------------
__global__ __launch_bounds__(256) void ln_gelu_kernel(const float* __restrict__ xs,
    u16* __restrict__ xsb, const float* __restrict__ g, const float* __restrict__ bta)
{
    const int row = blockIdx.x;
    const int tid = threadIdx.x;
    const float2 v = *(const float2*)&xs[(size_t)row * CC + tid * 2];
    float s  = v.x + v.y;
    float ss = v.x * v.x + v.y * v.y;
    #pragma unroll
    for (int o = 32; o > 0; o >>= 1) { s += __shfl_down(s, o); ss += __shfl_down(ss, o); }
    __shared__ float red[10];
    const int wid = tid >> 6;
    if ((tid & 63) == 0) { red[wid] = s; red[4 + wid] = ss; }
    __syncthreads();
    if (tid == 0) {
        const float S  = red[0] + red[1] + red[2] + red[3];
        const float SS = red[4] + red[5] + red[6] + red[7];
        const float mu = S * (1.0f / 512.0f);
        const float var = SS * (1.0f / 512.0f) - mu * mu;
        red[8] = mu;
        red[9] = 1.0f / sqrtf(var + 1e-5f);
    }
    __syncthreads();
    const float mu = red[8], inv = red[9];
    const float2 gg = *(const float2*)&g[tid * 2];
    const float2 bb = *(const float2*)&bta[tid * 2];
    float x0 = (v.x - mu) * inv * gg.x + bb.x;
    float x1 = (v.y - mu) * inv * gg.y + bb.y;
    x0 = 0.5f * x0 * (1.0f + erff(x0 * 0.70710678118654752f));
    x1 = 0.5f * x1 * (1.0f + erff(x1 * 0.70710678118654752f));
    ushort2 o; o.x = f2bf(x0); o.y = f2bf(x1);
    *(ushort2*)&xsb[(size_t)row * CC + tid * 2] = o;
}

// ---------------------------------------------------------------------------
// MFMA flash attention v3: swapped QK^T -> lane-local softmax rows.
// Block = 64 q-rows x (b,h); 4 waves x 16 q-rows. Per wave:
//   T[key][q] = mfma(K_frag, Q_frag): lane (r,g) holds keys {jt*16+4g+reg} of
//   q-row r. Softmax: in-lane over 16 + shfl_xor(16,32) over key-groups.
//   P packed in-register (v_cvt_pk_bf16_f32) -> PV A-fragment directly; V^T
//   was stored key-permuted by the producer GEMM so slots match. No P-LDS.
// ---------------------------------------------------------------------------
__global__ __launch_bounds__(256) void attn_mfma(const u16* __restrict__ q,
    const u16* __restrict__ kb, const u16* __restrict__ vt,
    const float* __restrict__ conf, u16* __restrict__ out)
{
    const int qt = blockIdx.x;              // 0..31
    const int bh = blockIdx.y;              // 0..63
    const int b = bh >> 3, h = bh & 7;
    const int tid = threadIdx.x;
    const int l = tid & 63, r = l & 15, g = l >> 4;
    const int w = tid >> 6;

    __shared__ u16 Kl[4096];                // 64 keys x 64 dims (8KB), swizzled
    __shared__ float confs[1024];           // per-block conf cache (4KB)

    #pragma unroll
    for (int cc = 0; cc < 4; ++cc)
        confs[tid + cc * 256] = conf[b * GM + cc * 256 + tid];

    // Q fragments (B-operand; row=q=r, k-slice d = g*8+{0..7}+32ks)
    short8 qf[2];
    {
        const u16* qp = q + ((size_t)(b * NN + qt * 64 + w * 16 + r)) * CC + h * HD + g * 8;
        qf[0] = *(const short8*)(qp);
        qf[1] = *(const short8*)(qp + 32);
    }

    const u16* vbase = vt + ((size_t)(b * 8 + h) * 64) * 1024;   // + d*1024 + keyslot

    f32x4 o[4] = {};
    float m_run = -1e30f, l_run = 0.0f;     // stats for q-row r (replicated over g)

    for (int kt = 0; kt < 16; ++kt) {
        // V^T fragments for this tile (L2-resident; key-permuted layout means
        // slot j here pairs with packed-P slot j below)
        short8 vfr[2][4];
        #pragma unroll
        for (int ks = 0; ks < 2; ++ks)
            #pragma unroll
            for (int ni = 0; ni < 4; ++ni)
                vfr[ks][ni] = *(const short8*)(vbase + (size_t)(ni * 16 + r) * 1024
                                               + kt * 64 + ks * 32 + g * 8);

        __syncthreads();
        // stage K tile (inverse-swizzled source -> linear LDS dest)
        #pragma unroll
        for (int it = 0; it < 2; ++it) {
            const int c = it * 256 + tid;
            const int row = c >> 3, s = c & 7;
            const int gg = s ^ (row & 7);
            const u16* gp = kb + ((size_t)(b * GM + kt * 64 + row)) * 512 + h * HD + gg * 8;
            __builtin_amdgcn_global_load_lds(gp,
                (u16*)((char*)Kl + it * 4096 + (tid & 192) * 16), 16, 0, 0);
        }
        __syncthreads();

        // ---- T = K @ Q^T (swapped): lane holds T[key=jt*16+4g+reg][q=r] ----
        f32x4 s4[4] = {};
        #pragma unroll
        for (int ks = 0; ks < 2; ++ks)
            #pragma unroll
            for (int jt = 0; jt < 4; ++jt) {
                const int key = jt * 16 + r;
                const short8 kf = *(const short8*)((char*)Kl + key * 128 +
                                                   (((ks * 4 + g) ^ (key & 7)) * 16));
                s4[jt] = __builtin_amdgcn_mfma_f32_16x16x32_bf16(kf, qf[ks], s4[jt], 0, 0, 0);
            }

        // ---- lane-local online softmax for q-row r ----
        float e[4][4];
        float mt = m_run;
        #pragma unroll
        for (int jt = 0; jt < 4; ++jt) {
            const f32x4 cf = *(const f32x4*)&confs[kt * 64 + jt * 16 + g * 4];
            #pragma unroll
            for (int reg = 0; reg < 4; ++reg) {
                const float L = s4[jt][reg] * 0.125f + cf[reg];
                e[jt][reg] = L;
                mt = fmaxf(mt, L);
            }
        }
        mt = fmaxf(mt, __shfl_xor(mt, 16, 64));
        mt = fmaxf(mt, __shfl_xor(mt, 32, 64));

        const float rf = __expf(m_run - mt);
        m_run = mt;
        float ps = 0.0f;
        #pragma unroll
        for (int jt = 0; jt < 4; ++jt)
            #pragma unroll
            for (int reg = 0; reg < 4; ++reg) {
                const float ev = __expf(e[jt][reg] - mt);
                e[jt][reg] = ev;
                ps += ev;
            }
        ps += __shfl_xor(ps, 16, 64);
        ps += __shfl_xor(ps, 32, 64);
        l_run = l_run * rf + ps;

        // pack P: w01[jt][p] = (bf16(e[jt][2p]) , bf16(e[jt][2p+1]))
        unsigned w01[4][2];
        #pragma unroll
        for (int jt = 0; jt < 4; ++jt) {
            w01[jt][0] = cvt_pk_bf16(e[jt][0], e[jt][1]);
            w01[jt][1] = cvt_pk_bf16(e[jt][2], e[jt][3]);
        }

        // rescale O (rows q=4g+reg; rf lives at lane q)
        float rfq[4];
        #pragma unroll
        for (int reg = 0; reg < 4; ++reg) rfq[reg] = __shfl(rf, g * 4 + reg, 64);
        #pragma unroll
        for (int ni = 0; ni < 4; ++ni)
            #pragma unroll
            for (int reg = 0; reg < 4; ++reg)
                o[ni][reg] *= rfq[reg];

        // ---- PV: A = packed P (lane-local), B = V^T fragments ----
        #pragma unroll
        for (int ks = 0; ks < 2; ++ks) {
            i32x4 paw;
            paw.x = (int)w01[2 * ks][0];
            paw.y = (int)w01[2 * ks][1];
            paw.z = (int)w01[2 * ks + 1][0];
            paw.w = (int)w01[2 * ks + 1][1];
            const short8 pa = __builtin_bit_cast(short8, paw);
            #pragma unroll
            for (int ni = 0; ni < 4; ++ni)
                o[ni] = __builtin_amdgcn_mfma_f32_16x16x32_bf16(pa, vfr[ks][ni], o[ni], 0, 0, 0);
        }
    }

    // epilogue: divide by l (stats live at lane q) and store bf16
    float lq[4];
    #pragma unroll
    for (int reg = 0; reg < 4; ++reg) lq[reg] = __shfl(l_run, g * 4 + reg, 64);
    const size_t orow = (size_t)(b * NN + qt * 64 + w * 16 + g * 4);
    #pragma unroll
    for (int ni = 0; ni < 4; ++ni)
        #pragma unroll
        for (int reg = 0; reg < 4; ++reg) {
            const float v = o[ni][reg] / lq[reg];
            out[(orow + reg) * CC + h * HD + ni * 16 + r] = f2bf(v);
        }
}

// ---------------------------------------------------------------------------
extern "C" void kernel_launch(void* const* d_in, const int* in_sizes, int n_in,
                              void* d_out, int out_size, void* d_ws, size_t ws_size,
                              hipStream_t stream)
{
    (void)in_sizes; (void)n_in; (void)out_size; (void)ws_size;
    const float* x        = (const float*)d_in[0];
    const float* x_source = (const float*)d_in[1];
    const float* loc      = (const float*)d_in[2];
    const float* conf_src = (const float*)d_in[3];
    const float* q_w      = (const float*)d_in[4];
    const float* kv_w     = (const float*)d_in[5];
    const float* sr_w     = (const float*)d_in[6];
    const float* sr_b     = (const float*)d_in[7];
    const float* ln_g     = (const float*)d_in[8];
    const float* ln_b     = (const float*)d_in[9];
    const float* proj_w   = (const float*)d_in[10];
    const float* proj_b   = (const float*)d_in[11];

    char* ws = (char*)d_ws;
    float* feat    = (float*)(ws + B_FEATF);
    float* xs      = (float*)(ws + B_XSF);
    float* cnt     = (float*)(ws + B_CNT);
    float* conf    = (float*)(ws + B_CONF);
    u16*   x_bf    = (u16*)(ws + B_XBF);
    u16*   kb_bf   = (u16*)(ws + B_KB);
    u16*   vt_bf   = (u16*)(ws + B_VT);
    u16*   feat_bf = (u16*)(ws + B_FEATBF);
    u16*   xs_bf   = (u16*)(ws + B_XSBF);
    u16*   wq_bf   = (u16*)(ws + B_WQ);
    u16*   wkv_bf  = (u16*)(ws + B_WKV);
    u16*   wsr_bf  = (u16*)(ws + B_WSR);
    u16*   wpr_bf  = (u16*)(ws + B_WPROJ);
    u16*   q_bf    = (u16*)(ws + B_XSF);    // reuse xs fp32 (dead after ln_gelu)
    u16*   attn_bf = (u16*)(ws + B_FEATF);  // reuse feat fp32 (dead after normalize)
    float* outp    = (float*)d_out;

    hipMemsetAsync(feat, 0, (size_t)8192 * 512 * sizeof(float), stream);
    hipMemsetAsync(cnt,  0, (size_t)16384 * sizeof(float), stream);   // cnt+conf contiguous

    // casts to bf16
    cast_bf16_kernel<<<8192, 256, 0, stream>>>(x, x_bf);            // 16384*512
    cast_bf16_kernel<<<256,  256, 0, stream>>>(q_w, wq_bf);         // 512*512
    cast_bf16_kernel<<<512,  256, 0, stream>>>(kv_w, wkv_bf);       // 1024*512
    cast_bf16_kernel<<<256,  256, 0, stream>>>(sr_w, wsr_bf);
    cast_bf16_kernel<<<256,  256, 0, stream>>>(proj_w, wpr_bf);

    // token2map
    scatter_kernel<<<BB * 2048, 256, 0, stream>>>(x_source, loc, conf_src, feat, cnt, conf);
    normalize_kernel<<<8192, 256, 0, stream>>>(feat, cnt, conf, feat_bf);

    // xs = feat @ sr_w^T + sr_b   (fp32 out for exact LN)
    gemm_mfma<true, 0><<<dim3(4, 64), 256, 0, stream>>>(feat_bf, wsr_bf, sr_b, xs, nullptr, nullptr, 8192, 512, 512);
    ln_gelu_kernel<<<8192, 256, 0, stream>>>(xs, xs_bf, ln_g, ln_b);

    // K = xs @ Wk^T  (bf16 out, [8192][512])
    gemm_mfma<false, 1><<<dim3(4, 64), 256, 0, stream>>>(xs_bf, wkv_bf, nullptr, nullptr, kb_bf, nullptr, 8192, 512, 512);

    // V^T = Wv @ xs^T  (operand-swapped GEMM; key-permuted transposed write)
    gemm_mfma<false, 2><<<dim3(64, 4), 256, 0, stream>>>(wkv_bf + (size_t)512 * 512, xs_bf, nullptr, nullptr, nullptr, vt_bf, 512, 8192, 512);

    // q = x @ q_w^T  (bf16 out, into old xs region)
    gemm_mfma<false, 1><<<dim3(4, 128), 256, 0, stream>>>(x_bf, wq_bf, nullptr, nullptr, q_bf, nullptr, 16384, 512, 512);

    // attention -> bf16 (into old feat region)
    attn_mfma<<<dim3(32, 64), 256, 0, stream>>>(q_bf, kb_bf, vt_bf, conf, attn_bf);

    // out = attn @ proj_w^T + proj_b  (fp32 out)
    gemm_mfma<true, 0><<<dim3(4, 128), 256, 0, stream>>>(attn_bf, wpr_bf, proj_b, outp, nullptr, nullptr, 16384, 512, 512);
}

// Round 5
// 352.389 us; speedup vs baseline: 1.2065x; 1.1566x over previous
//
#include <hip/hip_runtime.h>
#include <math.h>

typedef unsigned short u16;
typedef __attribute__((ext_vector_type(8))) short short8;
typedef __attribute__((ext_vector_type(4))) float f32x4;
typedef __attribute__((ext_vector_type(4))) int   i32x4;

// Problem constants (B=8, N=2048, Nsrc=2048, C=512, H=W=64, sr_ratio=2 -> 32x32 grid)
#define BB     8
#define NN     2048
#define CC     512
#define HEADS  8
#define HD     64
#define GM     1024   // 32*32 spatial tokens per batch

// Workspace byte offsets (total ~82.6 MB)
#define B_FEATF   ((size_t)0)                    // feat fp32 16MB; later attn_bf (16MB)
#define B_XSF     ((size_t)16*1024*1024)         // xs fp32 16MB; later q_bf (16MB)
#define B_XBF     ((size_t)32*1024*1024)         // x bf16 16MB
#define B_KB      ((size_t)48*1024*1024)         // K bf16 [8192][512] 8MB
#define B_VT      ((size_t)56*1024*1024)         // V^T bf16 [b][h][64][1024] 8MB (key-permuted)
#define B_FEATBF  ((size_t)64*1024*1024)         // feat bf16 8MB
#define B_XSBF    ((size_t)72*1024*1024)         // xs bf16 8MB
#define B_CNT     ((size_t)80*1024*1024)         // 32KB
#define B_CONF    (B_CNT + (size_t)32*1024)      // 32KB
#define B_WQ      (B_CNT + (size_t)64*1024)      // 512KB
#define B_WKV     (B_WQ  + (size_t)512*1024)     // 1MB
#define B_WSR     (B_WKV + (size_t)1024*1024)    // 512KB
#define B_WPROJ   (B_WSR + (size_t)512*1024)     // 512KB

__device__ __forceinline__ u16 f2bf(float f) {
    unsigned u = __float_as_uint(f);
    unsigned r = (u + 0x7fffu + ((u >> 16) & 1u)) >> 16;   // RNE
    return (u16)r;
}

__device__ __forceinline__ unsigned cvt_pk_bf16(float lo, float hi) {
    unsigned r;
    asm("v_cvt_pk_bf16_f32 %0, %1, %2" : "=v"(r) : "v"(lo), "v"(hi));
    return r;
}

// ---------------------------------------------------------------------------
// fp32 -> bf16 cast (grid*256 float4-quads)
// ---------------------------------------------------------------------------
__global__ __launch_bounds__(256) void cast_bf16_kernel(const float* __restrict__ in,
                                                        u16* __restrict__ out)
{
    const int i = blockIdx.x * 256 + threadIdx.x;
    const float4 v = ((const float4*)in)[i];
    ushort4 o;
    o.x = f2bf(v.x); o.y = f2bf(v.y); o.z = f2bf(v.z); o.w = f2bf(v.w);
    ((ushort4*)out)[i] = o;
}

// ---------------------------------------------------------------------------
// token2map scatter: one block per source token (fp32 atomics, exact)
// ---------------------------------------------------------------------------
__global__ __launch_bounds__(256) void scatter_kernel(const float* __restrict__ src_tok,
    const float* __restrict__ loc, const float* __restrict__ conf_src,
    float* __restrict__ feat, float* __restrict__ cnt, float* __restrict__ conf_acc)
{
    const int token = blockIdx.x;
    const int b = token >> 11;
    const int tid = threadIdx.x;

    float lx = loc[token * 2 + 0];
    float ly = loc[token * 2 + 1];
    lx = fminf(fmaxf(lx, -1.0f), 1.0f);
    ly = fminf(fmaxf(ly, -1.0f), 1.0f);
    const float pxf = rintf(0.5f * (lx + 1.0f) * 32.0f - 0.5f);   // round-half-even
    const float pyf = rintf(0.5f * (ly + 1.0f) * 32.0f - 0.5f);
    int x0 = (int)pxf; x0 = min(max(x0, 0), 31);
    int y0 = (int)pyf; y0 = min(max(y0, 0), 31);
    const int row = b * GM + y0 * 32 + x0;

    const float* s = src_tok + (size_t)token * CC;
    float* d = feat + (size_t)row * CC;
    atomicAdd(&d[tid],       s[tid]);
    atomicAdd(&d[tid + 256], s[tid + 256]);
    if (tid == 0) {
        atomicAdd(&cnt[row], 1.0f);
        atomicAdd(&conf_acc[row], conf_src[token]);
    }
}

// ---------------------------------------------------------------------------
// normalize: featb = bf16(feat/(cnt+1e-6) * (cnt>0)); conf likewise (in-place fp32)
// ---------------------------------------------------------------------------
__global__ __launch_bounds__(256) void normalize_kernel(const float* __restrict__ feat,
    const float* __restrict__ cnt, float* __restrict__ conf_acc, u16* __restrict__ featb)
{
    const int row = blockIdx.x;
    const int tid = threadIdx.x;
    const float cn = cnt[row];
    const float sc = (cn > 0.0f) ? (1.0f / (cn + 1e-6f)) : 0.0f;
    const float* f = feat + (size_t)row * CC;
    u16* o = featb + (size_t)row * CC;
    o[tid]       = f2bf(f[tid] * sc);
    o[tid + 256] = f2bf(f[tid + 256] * sc);
    if (tid == 0) conf_acc[row] *= sc;
}

// ---------------------------------------------------------------------------
// bf16 MFMA GEMM: C[M][Nn] = A[M][K] @ Bw[Nn][K]^T (+bias).
// 128x128 tile, BK=32, 4 waves (2x2), global_load_lds w=16, XOR-swizzled LDS.
// OUTMODE: 0 = fp32 out (Cf), 1 = bf16 out (Cb), 2 = V^T scatter-out (Vt):
//   rows are kv_w features (512 V-features), cols are tokens (b*1024+tok).
//   Token axis is PERMUTED within each 64-token tile so attention's PV
//   A-fragment (packed P registers) lines up slot-for-slot with V^T:
//   S(u) = 32*(u>>5) | 8*((u>>2)&3) | 4*((u>>4)&1) | (u&3).
// OUTMODE 3 = bf16 out scaled by 0.125 (attention Q pre-scale; exact in bf16).
// ---------------------------------------------------------------------------
template<bool BIAS, int OUTMODE>
__global__ __launch_bounds__(256) void gemm_mfma(const u16* __restrict__ A,
    const u16* __restrict__ Bw, const float* __restrict__ bias,
    float* __restrict__ Cf, u16* __restrict__ Cb, u16* __restrict__ Vt,
    int M, int Nn, int K)
{
    __shared__ u16 As[4096];   // 128 rows x 32 k (8KB)
    __shared__ u16 Bs[4096];
    const int tid = threadIdx.x;
    const int l = tid & 63, r = l & 15, g = l >> 4;
    const int w = tid >> 6, wm = w >> 1, wn = w & 1;
    const int m0 = blockIdx.y * 128, n0 = blockIdx.x * 128;

    f32x4 acc[4][4] = {};

    const int nkt = K >> 5;
    for (int kt = 0; kt < nkt; ++kt) {
        __syncthreads();
        #pragma unroll
        for (int it = 0; it < 2; ++it) {
            const int c = it * 256 + tid;
            const int row = c >> 2;
            const int gg = (c & 3) ^ ((row >> 2) & 3);   // inverse-swizzled source
            const u16* ga = A  + (size_t)(m0 + row) * K + kt * 32 + gg * 8;
            const u16* gb = Bw + (size_t)(n0 + row) * K + kt * 32 + gg * 8;
            u16* la = (u16*)((char*)As + it * 4096 + (tid & 192) * 16);  // wave-uniform
            u16* lb = (u16*)((char*)Bs + it * 4096 + (tid & 192) * 16);
            __builtin_amdgcn_global_load_lds(ga, la, 16, 0, 0);
            __builtin_amdgcn_global_load_lds(gb, lb, 16, 0, 0);
        }
        __syncthreads();

        short8 af[4], bf[4];
        #pragma unroll
        for (int mi = 0; mi < 4; ++mi) {
            const int row = wm * 64 + mi * 16 + r;
            af[mi] = *(const short8*)((char*)As + row * 64 + ((g ^ (r >> 2)) & 3) * 16);
        }
        #pragma unroll
        for (int ni = 0; ni < 4; ++ni) {
            const int row = wn * 64 + ni * 16 + r;
            bf[ni] = *(const short8*)((char*)Bs + row * 64 + ((g ^ (r >> 2)) & 3) * 16);
        }
        #pragma unroll
        for (int mi = 0; mi < 4; ++mi)
            #pragma unroll
            for (int ni = 0; ni < 4; ++ni)
                acc[mi][ni] = __builtin_amdgcn_mfma_f32_16x16x32_bf16(af[mi], bf[ni], acc[mi][ni], 0, 0, 0);
    }

    #pragma unroll
    for (int mi = 0; mi < 4; ++mi) {
        const int rbase = m0 + wm * 64 + mi * 16 + g * 4;   // C/D: row=(l>>4)*4+reg
        #pragma unroll
        for (int ni = 0; ni < 4; ++ni) {
            const int col = n0 + wn * 64 + ni * 16 + r;     // C/D: col=lane&15
            const float bv = BIAS ? bias[col] : 0.0f;
            #pragma unroll
            for (int reg = 0; reg < 4; ++reg) {
                const float v = acc[mi][ni][reg] + bv;
                if (OUTMODE == 0) {
                    Cf[(size_t)(rbase + reg) * Nn + col] = v;
                } else if (OUTMODE == 1) {
                    Cb[(size_t)(rbase + reg) * Nn + col] = f2bf(v);
                } else if (OUTMODE == 3) {
                    Cb[(size_t)(rbase + reg) * Nn + col] = f2bf(v * 0.125f);
                } else {
                    const int f = rbase + reg;              // V feature 0..511
                    const int head = f >> 6, d = f & 63;
                    const int bb2 = col >> 10, tok = col & 1023;
                    const int u = tok & 63;
                    const int S = ((u >> 5) << 5) | (((u >> 2) & 3) << 3)
                                | (((u >> 4) & 1) << 2) | (u & 3);
                    const int stok = (tok & ~63) | S;
                    Vt[(((size_t)bb2 * 8 + head) * 64 + d) * 1024 + stok] = f2bf(v);
                }
            }
        }
    }
}

// ---------------------------------------------------------------------------
// LayerNorm + exact GELU (fp32 in, bf16 out), one block per row of 512
// ---------------------------------------------------------------------------
__global__ __launch_bounds__(256) void ln_gelu_kernel(const float* __restrict__ xs,
    u16* __restrict__ xsb, const float* __restrict__ g, const float* __restrict__ bta)
{
    const int row = blockIdx.x;
    const int tid = threadIdx.x;
    const float2 v = *(const float2*)&xs[(size_t)row * CC + tid * 2];
    float s  = v.x + v.y;
    float ss = v.x * v.x + v.y * v.y;
    #pragma unroll
    for (int o = 32; o > 0; o >>= 1) { s += __shfl_down(s, o); ss += __shfl_down(ss, o); }
    __shared__ float red[10];
    const int wid = tid >> 6;
    if ((tid & 63) == 0) { red[wid] = s; red[4 + wid] = ss; }
    __syncthreads();
    if (tid == 0) {
        const float S  = red[0] + red[1] + red[2] + red[3];
        const float SS = red[4] + red[5] + red[6] + red[7];
        const float mu = S * (1.0f / 512.0f);
        const float var = SS * (1.0f / 512.0f) - mu * mu;
        red[8] = mu;
        red[9] = 1.0f / sqrtf(var + 1e-5f);
    }
    __syncthreads();
    const float mu = red[8], inv = red[9];
    const float2 gg = *(const float2*)&g[tid * 2];
    const float2 bb = *(const float2*)&bta[tid * 2];
    float x0 = (v.x - mu) * inv * gg.x + bb.x;
    float x1 = (v.y - mu) * inv * gg.y + bb.y;
    x0 = 0.5f * x0 * (1.0f + erff(x0 * 0.70710678118654752f));
    x1 = 0.5f * x1 * (1.0f + erff(x1 * 0.70710678118654752f));
    ushort2 o; o.x = f2bf(x0); o.y = f2bf(x1);
    *(ushort2*)&xsb[(size_t)row * CC + tid * 2] = o;
}

// ---------------------------------------------------------------------------
// MFMA flash attention v4: QBLK=128 (two 16-row Q fragments per wave),
// double-buffered K with ONE barrier per tile (stage kt+1 before computing kt),
// XCD-aware block swizzle (each XCD owns 8 bh slices -> K/V^T L2-resident).
// Swapped QK^T -> lane-local softmax; P packed in-register; V^T key-permuted
// by producer GEMM so packed-P slots line up. Q pre-scaled by 0.125.
// ---------------------------------------------------------------------------
__global__ __launch_bounds__(256) void attn_mfma(const u16* __restrict__ q,
    const u16* __restrict__ kb, const u16* __restrict__ vt,
    const float* __restrict__ conf, u16* __restrict__ out)
{
    const int bid = blockIdx.x;             // 0..1023
    const int xcd = bid & 7, slot = bid >> 3;
    const int bh = xcd * 8 + (slot & 7);    // 8 bh per XCD -> 2MB K+V^T per L2
    const int qt = slot >> 3;               // 0..15 (128 q-rows each)
    const int b = bh >> 3, h = bh & 7;
    const int tid = threadIdx.x;
    const int l = tid & 63, r = l & 15, g = l >> 4;
    const int w = tid >> 6;

    __shared__ u16 Kl[8192];                // 2 x (64 keys x 64 dims) dbuf (16KB)
    __shared__ float confs[1024];           // conf cache (4KB)

    #pragma unroll
    for (int cc = 0; cc < 4; ++cc)
        confs[tid + cc * 256] = conf[b * GM + cc * 256 + tid];

    // two Q fragments: q-rows qt*128 + w*32 + {0,16} + r (pre-scaled 0.125)
    short8 qa[2], qb_[2];
    {
        const u16* qp = q + ((size_t)(b * NN + qt * 128 + w * 32 + r)) * CC + h * HD + g * 8;
        qa[0]  = *(const short8*)(qp);
        qa[1]  = *(const short8*)(qp + 32);
        qb_[0] = *(const short8*)(qp + 16 * CC);
        qb_[1] = *(const short8*)(qp + 16 * CC + 32);
    }

    const u16* vbase = vt + ((size_t)(b * 8 + h) * 64) * 1024;   // + d*1024 + keyslot

    f32x4 oa[4] = {}, ob[4] = {};
    float ma = -1e30f, la = 0.0f, mb = -1e30f, lb = 0.0f;

    // prologue: stage K tile 0 into buffer 0
    #pragma unroll
    for (int it = 0; it < 2; ++it) {
        const int c = it * 256 + tid;
        const int row = c >> 3, s = c & 7;
        const int gg = s ^ (row & 7);
        const u16* gp = kb + ((size_t)(b * GM + row)) * 512 + h * HD + gg * 8;
        __builtin_amdgcn_global_load_lds(gp,
            (u16*)((char*)Kl + it * 4096 + (tid & 192) * 16), 16, 0, 0);
    }
    __syncthreads();    // drains stage (compiler vmcnt(0)) + covers conf preload

    for (int kt = 0; kt < 16; ++kt) {
        const int cur = kt & 1;

        // stage NEXT tile into the other buffer (issued before compute;
        // drained by this iteration's trailing barrier)
        if (kt + 1 < 16) {
            #pragma unroll
            for (int it = 0; it < 2; ++it) {
                const int c = it * 256 + tid;
                const int row = c >> 3, s = c & 7;
                const int gg = s ^ (row & 7);
                const u16* gp = kb + ((size_t)(b * GM + (kt + 1) * 64 + row)) * 512 + h * HD + gg * 8;
                __builtin_amdgcn_global_load_lds(gp,
                    (u16*)((char*)Kl + (cur ^ 1) * 8192 + it * 4096 + (tid & 192) * 16), 16, 0, 0);
            }
        }

        // V^T fragments for tile kt (L2-resident; key-permuted layout)
        short8 vfr[2][4];
        #pragma unroll
        for (int ks = 0; ks < 2; ++ks)
            #pragma unroll
            for (int ni = 0; ni < 4; ++ni)
                vfr[ks][ni] = *(const short8*)(vbase + (size_t)(ni * 16 + r) * 1024
                                               + kt * 64 + ks * 32 + g * 8);

        // ---- swapped QK^T, both halves share each K fragment ----
        f32x4 sa[4] = {}, sb[4] = {};
        #pragma unroll
        for (int ks = 0; ks < 2; ++ks)
            #pragma unroll
            for (int jt = 0; jt < 4; ++jt) {
                const int key = jt * 16 + r;
                const short8 kf = *(const short8*)((char*)Kl + cur * 8192 + key * 128 +
                                                   (((ks * 4 + g) ^ (key & 7)) * 16));
                sa[jt] = __builtin_amdgcn_mfma_f32_16x16x32_bf16(kf, qa[ks],  sa[jt], 0, 0, 0);
                sb[jt] = __builtin_amdgcn_mfma_f32_16x16x32_bf16(kf, qb_[ks], sb[jt], 0, 0, 0);
            }

        // ---- lane-local online softmax (both halves) ----
        float mta = ma, mtb = mb;
        #pragma unroll
        for (int jt = 0; jt < 4; ++jt) {
            const f32x4 cf = *(const f32x4*)&confs[kt * 64 + jt * 16 + g * 4];
            #pragma unroll
            for (int reg = 0; reg < 4; ++reg) {
                sa[jt][reg] += cf[reg];
                sb[jt][reg] += cf[reg];
                mta = fmaxf(mta, sa[jt][reg]);
                mtb = fmaxf(mtb, sb[jt][reg]);
            }
        }
        mta = fmaxf(mta, __shfl_xor(mta, 16, 64));
        mta = fmaxf(mta, __shfl_xor(mta, 32, 64));
        mtb = fmaxf(mtb, __shfl_xor(mtb, 16, 64));
        mtb = fmaxf(mtb, __shfl_xor(mtb, 32, 64));

        const float rfa = __expf(ma - mta);
        const float rfb = __expf(mb - mtb);
        ma = mta; mb = mtb;

        float psa = 0.0f, psb = 0.0f;
        #pragma unroll
        for (int jt = 0; jt < 4; ++jt)
            #pragma unroll
            for (int reg = 0; reg < 4; ++reg) {
                const float eva = __expf(sa[jt][reg] - mta);
                const float evb = __expf(sb[jt][reg] - mtb);
                sa[jt][reg] = eva; sb[jt][reg] = evb;
                psa += eva; psb += evb;
            }
        psa += __shfl_xor(psa, 16, 64);
        psa += __shfl_xor(psa, 32, 64);
        psb += __shfl_xor(psb, 16, 64);
        psb += __shfl_xor(psb, 32, 64);
        la = la * rfa + psa;
        lb = lb * rfb + psb;

        // pack P (bf16 pairs) for both halves
        unsigned wa[4][2], wb[4][2];
        #pragma unroll
        for (int jt = 0; jt < 4; ++jt) {
            wa[jt][0] = cvt_pk_bf16(sa[jt][0], sa[jt][1]);
            wa[jt][1] = cvt_pk_bf16(sa[jt][2], sa[jt][3]);
            wb[jt][0] = cvt_pk_bf16(sb[jt][0], sb[jt][1]);
            wb[jt][1] = cvt_pk_bf16(sb[jt][2], sb[jt][3]);
        }

        // rescale O (rows q=4g+reg; rf lives at lane q)
        float rfqa[4], rfqb[4];
        #pragma unroll
        for (int reg = 0; reg < 4; ++reg) {
            rfqa[reg] = __shfl(rfa, g * 4 + reg, 64);
            rfqb[reg] = __shfl(rfb, g * 4 + reg, 64);
        }
        #pragma unroll
        for (int ni = 0; ni < 4; ++ni)
            #pragma unroll
            for (int reg = 0; reg < 4; ++reg) {
                oa[ni][reg] *= rfqa[reg];
                ob[ni][reg] *= rfqb[reg];
            }

        // ---- PV: shared V^T fragments feed both halves ----
        #pragma unroll
        for (int ks = 0; ks < 2; ++ks) {
            i32x4 pwa, pwb;
            pwa.x = (int)wa[2 * ks][0];     pwa.y = (int)wa[2 * ks][1];
            pwa.z = (int)wa[2 * ks + 1][0]; pwa.w = (int)wa[2 * ks + 1][1];
            pwb.x = (int)wb[2 * ks][0];     pwb.y = (int)wb[2 * ks][1];
            pwb.z = (int)wb[2 * ks + 1][0]; pwb.w = (int)wb[2 * ks + 1][1];
            const short8 paa = __builtin_bit_cast(short8, pwa);
            const short8 pab = __builtin_bit_cast(short8, pwb);
            #pragma unroll
            for (int ni = 0; ni < 4; ++ni) {
                oa[ni] = __builtin_amdgcn_mfma_f32_16x16x32_bf16(paa, vfr[ks][ni], oa[ni], 0, 0, 0);
                ob[ni] = __builtin_amdgcn_mfma_f32_16x16x32_bf16(pab, vfr[ks][ni], ob[ni], 0, 0, 0);
            }
        }

        __syncthreads();   // one barrier/tile: drains next-stage, fences buffers
    }

    // epilogue: divide by l (stats live at lane q) and store bf16
    float lqa[4], lqb[4];
    #pragma unroll
    for (int reg = 0; reg < 4; ++reg) {
        lqa[reg] = __shfl(la, g * 4 + reg, 64);
        lqb[reg] = __shfl(lb, g * 4 + reg, 64);
    }
    const size_t orowa = (size_t)(b * NN + qt * 128 + w * 32 + g * 4);
    #pragma unroll
    for (int ni = 0; ni < 4; ++ni)
        #pragma unroll
        for (int reg = 0; reg < 4; ++reg) {
            out[(orowa + reg) * CC + h * HD + ni * 16 + r]      = f2bf(oa[ni][reg] / lqa[reg]);
            out[(orowa + 16 + reg) * CC + h * HD + ni * 16 + r] = f2bf(ob[ni][reg] / lqb[reg]);
        }
}

// ---------------------------------------------------------------------------
extern "C" void kernel_launch(void* const* d_in, const int* in_sizes, int n_in,
                              void* d_out, int out_size, void* d_ws, size_t ws_size,
                              hipStream_t stream)
{
    (void)in_sizes; (void)n_in; (void)out_size; (void)ws_size;
    const float* x        = (const float*)d_in[0];
    const float* x_source = (const float*)d_in[1];
    const float* loc      = (const float*)d_in[2];
    const float* conf_src = (const float*)d_in[3];
    const float* q_w      = (const float*)d_in[4];
    const float* kv_w     = (const float*)d_in[5];
    const float* sr_w     = (const float*)d_in[6];
    const float* sr_b     = (const float*)d_in[7];
    const float* ln_g     = (const float*)d_in[8];
    const float* ln_b     = (const float*)d_in[9];
    const float* proj_w   = (const float*)d_in[10];
    const float* proj_b   = (const float*)d_in[11];

    char* ws = (char*)d_ws;
    float* feat    = (float*)(ws + B_FEATF);
    float* xs      = (float*)(ws + B_XSF);
    float* cnt     = (float*)(ws + B_CNT);
    float* conf    = (float*)(ws + B_CONF);
    u16*   x_bf    = (u16*)(ws + B_XBF);
    u16*   kb_bf   = (u16*)(ws + B_KB);
    u16*   vt_bf   = (u16*)(ws + B_VT);
    u16*   feat_bf = (u16*)(ws + B_FEATBF);
    u16*   xs_bf   = (u16*)(ws + B_XSBF);
    u16*   wq_bf   = (u16*)(ws + B_WQ);
    u16*   wkv_bf  = (u16*)(ws + B_WKV);
    u16*   wsr_bf  = (u16*)(ws + B_WSR);
    u16*   wpr_bf  = (u16*)(ws + B_WPROJ);
    u16*   q_bf    = (u16*)(ws + B_XSF);    // reuse xs fp32 (dead after ln_gelu)
    u16*   attn_bf = (u16*)(ws + B_FEATF);  // reuse feat fp32 (dead after normalize)
    float* outp    = (float*)d_out;

    hipMemsetAsync(feat, 0, (size_t)8192 * 512 * sizeof(float), stream);
    hipMemsetAsync(cnt,  0, (size_t)16384 * sizeof(float), stream);   // cnt+conf contiguous

    // casts to bf16
    cast_bf16_kernel<<<8192, 256, 0, stream>>>(x, x_bf);            // 16384*512
    cast_bf16_kernel<<<256,  256, 0, stream>>>(q_w, wq_bf);         // 512*512
    cast_bf16_kernel<<<512,  256, 0, stream>>>(kv_w, wkv_bf);       // 1024*512
    cast_bf16_kernel<<<256,  256, 0, stream>>>(sr_w, wsr_bf);
    cast_bf16_kernel<<<256,  256, 0, stream>>>(proj_w, wpr_bf);

    // token2map
    scatter_kernel<<<BB * 2048, 256, 0, stream>>>(x_source, loc, conf_src, feat, cnt, conf);
    normalize_kernel<<<8192, 256, 0, stream>>>(feat, cnt, conf, feat_bf);

    // xs = feat @ sr_w^T + sr_b   (fp32 out for exact LN)
    gemm_mfma<true, 0><<<dim3(4, 64), 256, 0, stream>>>(feat_bf, wsr_bf, sr_b, xs, nullptr, nullptr, 8192, 512, 512);
    ln_gelu_kernel<<<8192, 256, 0, stream>>>(xs, xs_bf, ln_g, ln_b);

    // K = xs @ Wk^T  (bf16 out, [8192][512])
    gemm_mfma<false, 1><<<dim3(4, 64), 256, 0, stream>>>(xs_bf, wkv_bf, nullptr, nullptr, kb_bf, nullptr, 8192, 512, 512);

    // V^T = Wv @ xs^T  (operand-swapped GEMM; key-permuted transposed write)
    gemm_mfma<false, 2><<<dim3(64, 4), 256, 0, stream>>>(wkv_bf + (size_t)512 * 512, xs_bf, nullptr, nullptr, nullptr, vt_bf, 512, 8192, 512);

    // q = x @ q_w^T, pre-scaled by 0.125 (bf16 out, into old xs region)
    gemm_mfma<false, 3><<<dim3(4, 128), 256, 0, stream>>>(x_bf, wq_bf, nullptr, nullptr, q_bf, nullptr, 16384, 512, 512);

    // attention -> bf16 (into old feat region); XCD-swizzled 1-D grid
    attn_mfma<<<1024, 256, 0, stream>>>(q_bf, kb_bf, vt_bf, conf, attn_bf);

    // out = attn @ proj_w^T + proj_b  (fp32 out)
    gemm_mfma<true, 0><<<dim3(4, 128), 256, 0, stream>>>(attn_bf, wpr_bf, proj_b, outp, nullptr, nullptr, 16384, 512, 512);
}

// Round 7
// 324.945 us; speedup vs baseline: 1.3084x; 1.0845x over previous
//
#include <hip/hip_runtime.h>
#include <math.h>

typedef unsigned short u16;
typedef __attribute__((ext_vector_type(8))) short short8;
typedef __attribute__((ext_vector_type(4))) float f32x4;
typedef __attribute__((ext_vector_type(4))) int   i32x4;

// Problem constants (B=8, N=2048, Nsrc=2048, C=512, H=W=64, sr_ratio=2 -> 32x32 grid)
#define BB     8
#define NN     2048
#define CC     512
#define HEADS  8
#define HD     64
#define GM     1024   // 32*32 spatial tokens per batch

// Workspace byte offsets (total ~82.6 MB)
#define B_FEATF   ((size_t)0)                    // slots int[8192*128] 4MB; later attn_bf 16MB
#define B_XSF     ((size_t)16*1024*1024)         // xs fp32 16MB; later q_bf 16MB
#define B_XBF     ((size_t)32*1024*1024)         // x bf16 16MB
#define B_KB      ((size_t)48*1024*1024)         // K bf16 [8192][512] 8MB
#define B_VT      ((size_t)56*1024*1024)         // V^T bf16 [b][h][64][1024] 8MB (key-permuted)
#define B_FEATBF  ((size_t)64*1024*1024)         // feat bf16 8MB
#define B_XSBF    ((size_t)72*1024*1024)         // xs bf16 8MB
#define B_CNT     ((size_t)80*1024*1024)         // cnt int[8192] 32KB
#define B_CONF    (B_CNT + (size_t)32*1024)      // conf float[8192] 32KB
#define B_WQ      (B_CNT + (size_t)64*1024)      // 512KB
#define B_WKV     (B_WQ  + (size_t)512*1024)     // 1MB
#define B_WSR     (B_WKV + (size_t)1024*1024)    // 512KB
#define B_WPROJ   (B_WSR + (size_t)512*1024)     // 512KB

__device__ __forceinline__ u16 f2bf(float f) {
    unsigned u = __float_as_uint(f);
    unsigned r = (u + 0x7fffu + ((u >> 16) & 1u)) >> 16;   // RNE
    return (u16)r;
}

__device__ __forceinline__ unsigned cvt_pk_bf16(float lo, float hi) {
    unsigned r;
    asm("v_cvt_pk_bf16_f32 %0, %1, %2" : "=v"(r) : "v"(lo), "v"(hi));
    return r;
}

// ---------------------------------------------------------------------------
// all fp32->bf16 casts in ONE launch (segmented grid; each block = 256 float4)
// ---------------------------------------------------------------------------
__global__ __launch_bounds__(256) void cast_all_kernel(
    const float* __restrict__ x,      u16* __restrict__ x_bf,
    const float* __restrict__ q_w,    u16* __restrict__ wq_bf,
    const float* __restrict__ kv_w,   u16* __restrict__ wkv_bf,
    const float* __restrict__ sr_w,   u16* __restrict__ wsr_bf,
    const float* __restrict__ proj_w, u16* __restrict__ wpr_bf)
{
    const int bid = blockIdx.x;
    const float* src; u16* dst; int base;
    if      (bid < 8192) { src = x;      dst = x_bf;   base = bid; }
    else if (bid < 8448) { src = q_w;    dst = wq_bf;  base = bid - 8192; }
    else if (bid < 8960) { src = kv_w;   dst = wkv_bf; base = bid - 8448; }
    else if (bid < 9216) { src = sr_w;   dst = wsr_bf; base = bid - 8960; }
    else                 { src = proj_w; dst = wpr_bf; base = bid - 9216; }
    const int i = base * 256 + threadIdx.x;
    const float4 v = ((const float4*)src)[i];
    ushort4 o;
    o.x = f2bf(v.x); o.y = f2bf(v.y); o.z = f2bf(v.z); o.w = f2bf(v.w);
    ((ushort4*)dst)[i] = o;
}

// ---------------------------------------------------------------------------
// token2map pass 1: bucket tokens into per-cell slot lists (int atomics only)
// ---------------------------------------------------------------------------
__global__ __launch_bounds__(256) void scatter_idx_kernel(const float* __restrict__ loc,
    int* __restrict__ cnt_i, int* __restrict__ slots)
{
    const int token = blockIdx.x * 256 + threadIdx.x;     // 0..16383
    const int b = token >> 11;
    float lx = loc[token * 2 + 0];
    float ly = loc[token * 2 + 1];
    lx = fminf(fmaxf(lx, -1.0f), 1.0f);
    ly = fminf(fmaxf(ly, -1.0f), 1.0f);
    const float pxf = rintf(0.5f * (lx + 1.0f) * 32.0f - 0.5f);   // round-half-even
    const float pyf = rintf(0.5f * (ly + 1.0f) * 32.0f - 0.5f);
    int x0 = (int)pxf; x0 = min(max(x0, 0), 31);
    int y0 = (int)pyf; y0 = min(max(y0, 0), 31);
    const int row = b * GM + y0 * 32 + x0;
    const int slot = atomicAdd(&cnt_i[row], 1);
    if (slot < 128) slots[row * 128 + slot] = token;      // 128 >> max cell load (~62)
}

// ---------------------------------------------------------------------------
// token2map pass 2: gather-reduce + normalize, bf16 feat out + conf out.
// One block per cell; coalesced full-row reads of member tokens.
// ---------------------------------------------------------------------------
__global__ __launch_bounds__(256) void gather_reduce_kernel(
    const float* __restrict__ x_source, const float* __restrict__ conf_src,
    const int* __restrict__ cnt_i, const int* __restrict__ slots,
    u16* __restrict__ featb, float* __restrict__ conf)
{
    const int row = blockIdx.x;            // 0..8191
    const int tid = threadIdx.x;
    const int n0 = cnt_i[row];
    const int n = min(n0, 128);

    float a0 = 0.0f, a1 = 0.0f;
    #pragma unroll 2
    for (int t = 0; t < n; ++t) {
        const int tok = slots[row * 128 + t];
        const float* s = x_source + (size_t)tok * CC;
        a0 += s[tid];
        a1 += s[tid + 256];
    }

    // conf sum: lanes 0..n-1 (two waves) load, shuffle-reduce, combine in LDS
    __shared__ float cred[2];
    float cv = (tid < n) ? conf_src[slots[row * 128 + tid]] : 0.0f;
    if (tid < 128) {
        #pragma unroll
        for (int o = 32; o > 0; o >>= 1) cv += __shfl_down(cv, o, 64);
        if ((tid & 63) == 0) cred[tid >> 6] = cv;
    }
    __syncthreads();

    const float fn = (float)n0;
    const float sc = (n0 > 0) ? (1.0f / (fn + 1e-6f)) : 0.0f;
    u16* o = featb + (size_t)row * CC;
    o[tid]       = f2bf(a0 * sc);
    o[tid + 256] = f2bf(a1 * sc);
    if (tid == 0) conf[row] = (cred[0] + cred[1]) * sc;
}

// ---------------------------------------------------------------------------
// bf16 MFMA GEMM body: C[M][Nn] = A[M][K] @ Bw[Nn][K]^T (+bias).
// 128x128 tile, BK=32, 4 waves (2x2), global_load_lds w=16, XOR-swizzled LDS,
// DOUBLE-BUFFERED: stage kt+1 before computing kt, ONE barrier per tile.
// smem: 32KB = As[2][4096] ++ Bs[2][4096] (u16).
// OUTMODE: 0 = fp32 out, 1 = bf16 out, 2 = V^T key-permuted scatter-out,
//          3 = bf16 out scaled 0.125 (attention Q pre-scale).
// ---------------------------------------------------------------------------
template<bool BIAS, int OUTMODE>
__device__ __forceinline__ void gemm_body(int bx, int by,
    const u16* __restrict__ A, const u16* __restrict__ Bw,
    const float* __restrict__ bias,
    float* __restrict__ Cf, u16* __restrict__ Cb, u16* __restrict__ Vt,
    int M, int Nn, int K, u16* sm)
{
    u16* As = sm;            // [2][4096]
    u16* Bs = sm + 8192;     // [2][4096]
    const int tid = threadIdx.x;
    const int l = tid & 63, r = l & 15, g = l >> 4;
    const int w = tid >> 6, wm = w >> 1, wn = w & 1;
    const int m0 = by * 128, n0 = bx * 128;

    f32x4 acc[4][4] = {};
    const int nkt = K >> 5;

    // prologue: stage kt=0 into buffer 0
    #pragma unroll
    for (int it = 0; it < 2; ++it) {
        const int c = it * 256 + tid;
        const int row = c >> 2;
        const int gg = (c & 3) ^ ((row >> 2) & 3);
        __builtin_amdgcn_global_load_lds(A  + (size_t)(m0 + row) * K + gg * 8,
            (u16*)((char*)As + it * 4096 + (tid & 192) * 16), 16, 0, 0);
        __builtin_amdgcn_global_load_lds(Bw + (size_t)(n0 + row) * K + gg * 8,
            (u16*)((char*)Bs + it * 4096 + (tid & 192) * 16), 16, 0, 0);
    }
    __syncthreads();

    for (int kt = 0; kt < nkt; ++kt) {
        const int cur = kt & 1;
        if (kt + 1 < nkt) {
            #pragma unroll
            for (int it = 0; it < 2; ++it) {
                const int c = it * 256 + tid;
                const int row = c >> 2;
                const int gg = (c & 3) ^ ((row >> 2) & 3);
                __builtin_amdgcn_global_load_lds(A  + (size_t)(m0 + row) * K + (kt + 1) * 32 + gg * 8,
                    (u16*)((char*)As + (cur ^ 1) * 8192 + it * 4096 + (tid & 192) * 16), 16, 0, 0);
                __builtin_amdgcn_global_load_lds(Bw + (size_t)(n0 + row) * K + (kt + 1) * 32 + gg * 8,
                    (u16*)((char*)Bs + (cur ^ 1) * 8192 + it * 4096 + (tid & 192) * 16), 16, 0, 0);
            }
        }

        short8 af[4], bf[4];
        #pragma unroll
        for (int mi = 0; mi < 4; ++mi) {
            const int row = wm * 64 + mi * 16 + r;
            af[mi] = *(const short8*)((char*)As + cur * 8192 + row * 64 + ((g ^ (r >> 2)) & 3) * 16);
        }
        #pragma unroll
        for (int ni = 0; ni < 4; ++ni) {
            const int row = wn * 64 + ni * 16 + r;
            bf[ni] = *(const short8*)((char*)Bs + cur * 8192 + row * 64 + ((g ^ (r >> 2)) & 3) * 16);
        }
        #pragma unroll
        for (int mi = 0; mi < 4; ++mi)
            #pragma unroll
            for (int ni = 0; ni < 4; ++ni)
                acc[mi][ni] = __builtin_amdgcn_mfma_f32_16x16x32_bf16(af[mi], bf[ni], acc[mi][ni], 0, 0, 0);

        __syncthreads();   // drains next-stage loads + fences LDS reuse
    }

    #pragma unroll
    for (int mi = 0; mi < 4; ++mi) {
        const int rbase = m0 + wm * 64 + mi * 16 + g * 4;   // C/D: row=(l>>4)*4+reg
        #pragma unroll
        for (int ni = 0; ni < 4; ++ni) {
            const int col = n0 + wn * 64 + ni * 16 + r;     // C/D: col=lane&15
            const float bv = BIAS ? bias[col] : 0.0f;
            #pragma unroll
            for (int reg = 0; reg < 4; ++reg) {
                const float v = acc[mi][ni][reg] + bv;
                if (OUTMODE == 0) {
                    Cf[(size_t)(rbase + reg) * Nn + col] = v;
                } else if (OUTMODE == 1) {
                    Cb[(size_t)(rbase + reg) * Nn + col] = f2bf(v);
                } else if (OUTMODE == 3) {
                    Cb[(size_t)(rbase + reg) * Nn + col] = f2bf(v * 0.125f);
                } else {
                    const int f = rbase + reg;              // V feature 0..511
                    const int head = f >> 6, d = f & 63;
                    const int bb2 = col >> 10, tok = col & 1023;
                    const int u = tok & 63;
                    const int S = ((u >> 5) << 5) | (((u >> 2) & 3) << 3)
                                | (((u >> 4) & 1) << 2) | (u & 3);
                    const int stok = (tok & ~63) | S;
                    Vt[(((size_t)bb2 * 8 + head) * 64 + d) * 1024 + stok] = f2bf(v);
                }
            }
        }
    }
}

// standalone GEMM (sr, proj)
template<bool BIAS, int OUTMODE>
__global__ __launch_bounds__(256) void gemm_single(const u16* __restrict__ A,
    const u16* __restrict__ Bw, const float* __restrict__ bias,
    float* __restrict__ Cf, u16* __restrict__ Cb, u16* __restrict__ Vt,
    int M, int Nn, int K)
{
    __shared__ u16 sm[16384];
    gemm_body<BIAS, OUTMODE>(blockIdx.x, blockIdx.y, A, Bw, bias, Cf, Cb, Vt, M, Nn, K, sm);
}

// fused K + V^T + Q GEMMs (all inputs ready after ln_gelu): 1024 blocks
__global__ __launch_bounds__(256) void gemm_kvq_kernel(
    const u16* __restrict__ xs_bf, const u16* __restrict__ wkv_bf,
    u16* __restrict__ kb_bf, u16* __restrict__ vt_bf,
    const u16* __restrict__ x_bf, const u16* __restrict__ wq_bf,
    u16* __restrict__ q_bf)
{
    __shared__ u16 sm[16384];
    const int bid = blockIdx.x;
    if (bid < 256) {
        // K = xs @ Wk^T   (M=8192, N=512)
        gemm_body<false, 1>(bid & 3, bid >> 2, xs_bf, wkv_bf, nullptr,
                            nullptr, kb_bf, nullptr, 8192, 512, 512, sm);
    } else if (bid < 512) {
        // V^T = Wv @ xs^T (M=512, N=8192), key-permuted transposed write
        const int id = bid - 256;
        gemm_body<false, 2>(id & 63, id >> 6, wkv_bf + (size_t)512 * 512, xs_bf, nullptr,
                            nullptr, nullptr, vt_bf, 512, 8192, 512, sm);
    } else {
        // q = (x @ q_w^T) * 0.125   (M=16384, N=512)
        const int id = bid - 512;
        gemm_body<false, 3>(id & 3, id >> 2, x_bf, wq_bf, nullptr,
                            nullptr, q_bf, nullptr, 16384, 512, 512, sm);
    }
}

// ---------------------------------------------------------------------------
// LayerNorm + exact GELU (fp32 in, bf16 out), one block per row of 512
// ---------------------------------------------------------------------------
__global__ __launch_bounds__(256) void ln_gelu_kernel(const float* __restrict__ xs,
    u16* __restrict__ xsb, const float* __restrict__ g, const float* __restrict__ bta)
{
    const int row = blockIdx.x;
    const int tid = threadIdx.x;
    const float2 v = *(const float2*)&xs[(size_t)row * CC + tid * 2];
    float s  = v.x + v.y;
    float ss = v.x * v.x + v.y * v.y;
    #pragma unroll
    for (int o = 32; o > 0; o >>= 1) { s += __shfl_down(s, o); ss += __shfl_down(ss, o); }
    __shared__ float red[10];
    const int wid = tid >> 6;
    if ((tid & 63) == 0) { red[wid] = s; red[4 + wid] = ss; }
    __syncthreads();
    if (tid == 0) {
        const float S  = red[0] + red[1] + red[2] + red[3];
        const float SS = red[4] + red[5] + red[6] + red[7];
        const float mu = S * (1.0f / 512.0f);
        const float var = SS * (1.0f / 512.0f) - mu * mu;
        red[8] = mu;
        red[9] = 1.0f / sqrtf(var + 1e-5f);
    }
    __syncthreads();
    const float mu = red[8], inv = red[9];
    const float2 gg = *(const float2*)&g[tid * 2];
    const float2 bb = *(const float2*)&bta[tid * 2];
    float x0 = (v.x - mu) * inv * gg.x + bb.x;
    float x1 = (v.y - mu) * inv * gg.y + bb.y;
    x0 = 0.5f * x0 * (1.0f + erff(x0 * 0.70710678118654752f));
    x1 = 0.5f * x1 * (1.0f + erff(x1 * 0.70710678118654752f));
    ushort2 o; o.x = f2bf(x0); o.y = f2bf(x1);
    *(ushort2*)&xsb[(size_t)row * CC + tid * 2] = o;
}

// ---------------------------------------------------------------------------
// MFMA flash attention v5: v4 + defer-max (T13, THR=8).
// QBLK=128, dbuf K (one barrier/tile), XCD swizzle, swapped QK^T,
// lane-local softmax, in-register packed P, key-permuted V^T.
// ---------------------------------------------------------------------------
__global__ __launch_bounds__(256) void attn_mfma(const u16* __restrict__ q,
    const u16* __restrict__ kb, const u16* __restrict__ vt,
    const float* __restrict__ conf, u16* __restrict__ out)
{
    const int bid = blockIdx.x;             // 0..1023
    const int xcd = bid & 7, slot = bid >> 3;
    const int bh = xcd * 8 + (slot & 7);    // 8 bh per XCD -> K+V^T L2-resident
    const int qt = slot >> 3;               // 0..15
    const int b = bh >> 3, h = bh & 7;
    const int tid = threadIdx.x;
    const int l = tid & 63, r = l & 15, g = l >> 4;
    const int w = tid >> 6;

    __shared__ u16 Kl[8192];                // 2 x (64 keys x 64 dims) dbuf (16KB)
    __shared__ float confs[1024];           // conf cache (4KB)

    #pragma unroll
    for (int cc = 0; cc < 4; ++cc)
        confs[tid + cc * 256] = conf[b * GM + cc * 256 + tid];

    short8 qa[2], qb_[2];
    {
        const u16* qp = q + ((size_t)(b * NN + qt * 128 + w * 32 + r)) * CC + h * HD + g * 8;
        qa[0]  = *(const short8*)(qp);
        qa[1]  = *(const short8*)(qp + 32);
        qb_[0] = *(const short8*)(qp + 16 * CC);
        qb_[1] = *(const short8*)(qp + 16 * CC + 32);
    }

    const u16* vbase = vt + ((size_t)(b * 8 + h) * 64) * 1024;

    f32x4 oa[4] = {}, ob[4] = {};
    float ma = -1e30f, la = 0.0f, mb = -1e30f, lb = 0.0f;

    // prologue: stage K tile 0 into buffer 0
    #pragma unroll
    for (int it = 0; it < 2; ++it) {
        const int c = it * 256 + tid;
        const int row = c >> 3, s = c & 7;
        const int gg = s ^ (row & 7);
        __builtin_amdgcn_global_load_lds(kb + ((size_t)(b * GM + row)) * 512 + h * HD + gg * 8,
            (u16*)((char*)Kl + it * 4096 + (tid & 192) * 16), 16, 0, 0);
    }
    __syncthreads();

    for (int kt = 0; kt < 16; ++kt) {
        const int cur = kt & 1;

        if (kt + 1 < 16) {
            #pragma unroll
            for (int it = 0; it < 2; ++it) {
                const int c = it * 256 + tid;
                const int row = c >> 3, s = c & 7;
                const int gg = s ^ (row & 7);
                __builtin_amdgcn_global_load_lds(
                    kb + ((size_t)(b * GM + (kt + 1) * 64 + row)) * 512 + h * HD + gg * 8,
                    (u16*)((char*)Kl + (cur ^ 1) * 8192 + it * 4096 + (tid & 192) * 16), 16, 0, 0);
            }
        }

        short8 vfr[2][4];
        #pragma unroll
        for (int ks = 0; ks < 2; ++ks)
            #pragma unroll
            for (int ni = 0; ni < 4; ++ni)
                vfr[ks][ni] = *(const short8*)(vbase + (size_t)(ni * 16 + r) * 1024
                                               + kt * 64 + ks * 32 + g * 8);

        // ---- swapped QK^T ----
        f32x4 sa[4] = {}, sb[4] = {};
        #pragma unroll
        for (int ks = 0; ks < 2; ++ks)
            #pragma unroll
            for (int jt = 0; jt < 4; ++jt) {
                const int key = jt * 16 + r;
                const short8 kf = *(const short8*)((char*)Kl + cur * 8192 + key * 128 +
                                                   (((ks * 4 + g) ^ (key & 7)) * 16));
                sa[jt] = __builtin_amdgcn_mfma_f32_16x16x32_bf16(kf, qa[ks],  sa[jt], 0, 0, 0);
                sb[jt] = __builtin_amdgcn_mfma_f32_16x16x32_bf16(kf, qb_[ks], sb[jt], 0, 0, 0);
            }

        // ---- lane-local online softmax with defer-max (THR=8) ----
        float tma = -1e30f, tmb = -1e30f;
        #pragma unroll
        for (int jt = 0; jt < 4; ++jt) {
            const f32x4 cf = *(const f32x4*)&confs[kt * 64 + jt * 16 + g * 4];
            #pragma unroll
            for (int reg = 0; reg < 4; ++reg) {
                sa[jt][reg] += cf[reg];
                sb[jt][reg] += cf[reg];
                tma = fmaxf(tma, sa[jt][reg]);
                tmb = fmaxf(tmb, sb[jt][reg]);
            }
        }
        tma = fmaxf(tma, __shfl_xor(tma, 16, 64));
        tma = fmaxf(tma, __shfl_xor(tma, 32, 64));
        tmb = fmaxf(tmb, __shfl_xor(tmb, 16, 64));
        tmb = fmaxf(tmb, __shfl_xor(tmb, 32, 64));

        if (!__all(tma <= ma + 8.0f)) {
            const float mta = fmaxf(ma, tma);
            const float rfa = __expf(ma - mta);
            ma = mta;
            la *= rfa;
            float rfq[4];
            #pragma unroll
            for (int reg = 0; reg < 4; ++reg) rfq[reg] = __shfl(rfa, g * 4 + reg, 64);
            #pragma unroll
            for (int ni = 0; ni < 4; ++ni)
                #pragma unroll
                for (int reg = 0; reg < 4; ++reg) oa[ni][reg] *= rfq[reg];
        }
        if (!__all(tmb <= mb + 8.0f)) {
            const float mtb = fmaxf(mb, tmb);
            const float rfb = __expf(mb - mtb);
            mb = mtb;
            lb *= rfb;
            float rfq[4];
            #pragma unroll
            for (int reg = 0; reg < 4; ++reg) rfq[reg] = __shfl(rfb, g * 4 + reg, 64);
            #pragma unroll
            for (int ni = 0; ni < 4; ++ni)
                #pragma unroll
                for (int reg = 0; reg < 4; ++reg) ob[ni][reg] *= rfq[reg];
        }

        float psa = 0.0f, psb = 0.0f;
        #pragma unroll
        for (int jt = 0; jt < 4; ++jt)
            #pragma unroll
            for (int reg = 0; reg < 4; ++reg) {
                const float eva = __expf(sa[jt][reg] - ma);
                const float evb = __expf(sb[jt][reg] - mb);
                sa[jt][reg] = eva; sb[jt][reg] = evb;
                psa += eva; psb += evb;
            }
        psa += __shfl_xor(psa, 16, 64);
        psa += __shfl_xor(psa, 32, 64);
        psb += __shfl_xor(psb, 16, 64);
        psb += __shfl_xor(psb, 32, 64);
        la += psa;
        lb += psb;

        // pack P (bf16 pairs)
        unsigned wa[4][2], wb[4][2];
        #pragma unroll
        for (int jt = 0; jt < 4; ++jt) {
            wa[jt][0] = cvt_pk_bf16(sa[jt][0], sa[jt][1]);
            wa[jt][1] = cvt_pk_bf16(sa[jt][2], sa[jt][3]);
            wb[jt][0] = cvt_pk_bf16(sb[jt][0], sb[jt][1]);
            wb[jt][1] = cvt_pk_bf16(sb[jt][2], sb[jt][3]);
        }

        // ---- PV ----
        #pragma unroll
        for (int ks = 0; ks < 2; ++ks) {
            i32x4 pwa, pwb;
            pwa.x = (int)wa[2 * ks][0];     pwa.y = (int)wa[2 * ks][1];
            pwa.z = (int)wa[2 * ks + 1][0]; pwa.w = (int)wa[2 * ks + 1][1];
            pwb.x = (int)wb[2 * ks][0];     pwb.y = (int)wb[2 * ks][1];
            pwb.z = (int)wb[2 * ks + 1][0]; pwb.w = (int)wb[2 * ks + 1][1];
            const short8 paa = __builtin_bit_cast(short8, pwa);
            const short8 pab = __builtin_bit_cast(short8, pwb);
            #pragma unroll
            for (int ni = 0; ni < 4; ++ni) {
                oa[ni] = __builtin_amdgcn_mfma_f32_16x16x32_bf16(paa, vfr[ks][ni], oa[ni], 0, 0, 0);
                ob[ni] = __builtin_amdgcn_mfma_f32_16x16x32_bf16(pab, vfr[ks][ni], ob[ni], 0, 0, 0);
            }
        }

        __syncthreads();   // one barrier/tile
    }

    float lqa[4], lqb[4];
    #pragma unroll
    for (int reg = 0; reg < 4; ++reg) {
        lqa[reg] = __shfl(la, g * 4 + reg, 64);
        lqb[reg] = __shfl(lb, g * 4 + reg, 64);
    }
    const size_t orowa = (size_t)(b * NN + qt * 128 + w * 32 + g * 4);
    #pragma unroll
    for (int ni = 0; ni < 4; ++ni)
        #pragma unroll
        for (int reg = 0; reg < 4; ++reg) {
            out[(orowa + reg) * CC + h * HD + ni * 16 + r]      = f2bf(oa[ni][reg] / lqa[reg]);
            out[(orowa + 16 + reg) * CC + h * HD + ni * 16 + r] = f2bf(ob[ni][reg] / lqb[reg]);
        }
}

// ---------------------------------------------------------------------------
extern "C" void kernel_launch(void* const* d_in, const int* in_sizes, int n_in,
                              void* d_out, int out_size, void* d_ws, size_t ws_size,
                              hipStream_t stream)
{
    (void)in_sizes; (void)n_in; (void)out_size; (void)ws_size;
    const float* x        = (const float*)d_in[0];
    const float* x_source = (const float*)d_in[1];
    const float* loc      = (const float*)d_in[2];
    const float* conf_src = (const float*)d_in[3];
    const float* q_w      = (const float*)d_in[4];
    const float* kv_w     = (const float*)d_in[5];
    const float* sr_w     = (const float*)d_in[6];
    const float* sr_b     = (const float*)d_in[7];
    const float* ln_g     = (const float*)d_in[8];
    const float* ln_b     = (const float*)d_in[9];
    const float* proj_w   = (const float*)d_in[10];
    const float* proj_b   = (const float*)d_in[11];

    char* ws = (char*)d_ws;
    int*   slots   = (int*)(ws + B_FEATF);    // 4MB, dead before attn_bf is written
    float* xs      = (float*)(ws + B_XSF);
    int*   cnt_i   = (int*)(ws + B_CNT);
    float* conf    = (float*)(ws + B_CONF);
    u16*   x_bf    = (u16*)(ws + B_XBF);
    u16*   kb_bf   = (u16*)(ws + B_KB);
    u16*   vt_bf   = (u16*)(ws + B_VT);
    u16*   feat_bf = (u16*)(ws + B_FEATBF);
    u16*   xs_bf   = (u16*)(ws + B_XSBF);
    u16*   wq_bf   = (u16*)(ws + B_WQ);
    u16*   wkv_bf  = (u16*)(ws + B_WKV);
    u16*   wsr_bf  = (u16*)(ws + B_WSR);
    u16*   wpr_bf  = (u16*)(ws + B_WPROJ);
    u16*   q_bf    = (u16*)(ws + B_XSF);      // reuse xs fp32 (dead after ln_gelu)
    u16*   attn_bf = (u16*)(ws + B_FEATF);    // reuse slots region (dead after gather)
    float* outp    = (float*)d_out;

    hipMemsetAsync(cnt_i, 0, 8192 * sizeof(int), stream);

    // all casts in one launch
    cast_all_kernel<<<9472, 256, 0, stream>>>(x, x_bf, q_w, wq_bf, kv_w, wkv_bf,
                                              sr_w, wsr_bf, proj_w, wpr_bf);

    // token2map: bucket + gather-reduce (writes bf16 feat + conf directly)
    scatter_idx_kernel<<<64, 256, 0, stream>>>(loc, cnt_i, slots);
    gather_reduce_kernel<<<8192, 256, 0, stream>>>(x_source, conf_src, cnt_i, slots,
                                                   feat_bf, conf);

    // xs = feat @ sr_w^T + sr_b   (fp32 out for exact LN)
    gemm_single<true, 0><<<dim3(4, 64), 256, 0, stream>>>(feat_bf, wsr_bf, sr_b,
                                                          xs, nullptr, nullptr, 8192, 512, 512);
    ln_gelu_kernel<<<8192, 256, 0, stream>>>(xs, xs_bf, ln_g, ln_b);

    // K + V^T + q in one launch (1024 blocks)
    gemm_kvq_kernel<<<1024, 256, 0, stream>>>(xs_bf, wkv_bf, kb_bf, vt_bf,
                                              x_bf, wq_bf, q_bf);

    // attention -> bf16 (into old slots region); XCD-swizzled 1-D grid
    attn_mfma<<<1024, 256, 0, stream>>>(q_bf, kb_bf, vt_bf, conf, attn_bf);

    // out = attn @ proj_w^T + proj_b  (fp32 out)
    gemm_single<true, 0><<<dim3(4, 128), 256, 0, stream>>>(attn_bf, wpr_bf, proj_b,
                                                           outp, nullptr, nullptr, 16384, 512, 512);
}